// Round 10
// baseline (370.443 us; speedup 1.0000x reference)
//
#include <hip/hip_runtime.h>
#include <hip/hip_fp16.h>
#include <math.h>

#define NN 50000
#define NE 800000
#define EPSV 1e-5f
#define SCAN_NB 49   // ceil(NN / 1024)

typedef _Float16 h2f __attribute__((ext_vector_type(2)));

// ---------------- degree count ----------------
__global__ void deg_kernel(const int* __restrict__ dst, int* __restrict__ deg, int E) {
    int e = blockIdx.x * blockDim.x + threadIdx.x;
    if (e < E) atomicAdd(&deg[dst[e]], 1);
}

// ---------------- 3-phase grid-wide exclusive scan of deg -> rowptr, cursor ----------------
__global__ void scan_phaseA(const int* __restrict__ deg, int* __restrict__ blocksum) {
    __shared__ int wsums[4];
    int t = threadIdx.x;
    int base = blockIdx.x * 1024 + t * 4;
    int s = 0;
    if (base + 3 < NN) {
        int4 d = *reinterpret_cast<const int4*>(deg + base);
        s = d.x + d.y + d.z + d.w;
    } else {
        for (int j = 0; j < 4; ++j) if (base + j < NN) s += deg[base + j];
    }
#pragma unroll
    for (int o = 1; o < 64; o <<= 1) s += __shfl_xor(s, o, 64);
    if ((t & 63) == 0) wsums[t >> 6] = s;
    __syncthreads();
    if (t == 0) blocksum[blockIdx.x] = wsums[0] + wsums[1] + wsums[2] + wsums[3];
}

__global__ void scan_phaseB(int* __restrict__ blocksum) {
    int t = threadIdx.x;  // 64 threads
    int v = (t < SCAN_NB) ? blocksum[t] : 0;
    int incl = v;
#pragma unroll
    for (int o = 1; o < 64; o <<= 1) {
        int nv = __shfl_up(incl, o, 64);
        if (t >= o) incl += nv;
    }
    if (t < SCAN_NB) blocksum[t] = incl - v;  // exclusive
}

__global__ void scan_phaseC(const int* __restrict__ deg, const int* __restrict__ blocksum,
                            int* __restrict__ rowptr, int* __restrict__ cursor) {
    __shared__ int woff[4];
    int t = threadIdx.x;
    int base = blockIdx.x * 1024 + t * 4;
    int d0 = 0, d1 = 0, d2 = 0, d3 = 0;
    if (base + 3 < NN) {
        int4 d = *reinterpret_cast<const int4*>(deg + base);
        d0 = d.x; d1 = d.y; d2 = d.z; d3 = d.w;
    } else {
        if (base + 0 < NN) d0 = deg[base + 0];
        if (base + 1 < NN) d1 = deg[base + 1];
        if (base + 2 < NN) d2 = deg[base + 2];
        if (base + 3 < NN) d3 = deg[base + 3];
    }
    int ts = d0 + d1 + d2 + d3;
    int lane = t & 63, w = t >> 6;
    int incl = ts;
#pragma unroll
    for (int o = 1; o < 64; o <<= 1) {
        int nv = __shfl_up(incl, o, 64);
        if (lane >= o) incl += nv;
    }
    if (lane == 63) woff[w] = incl;
    __syncthreads();
    if (t == 0) {
        int r = 0;
#pragma unroll
        for (int i = 0; i < 4; ++i) { int v = woff[i]; woff[i] = r; r += v; }
    }
    __syncthreads();
    int run = blocksum[blockIdx.x] + woff[w] + incl - ts;
    int r0 = run, r1 = r0 + d0, r2 = r1 + d1, r3 = r2 + d2;
    if (base + 3 < NN) {
        int4 rv; rv.x = r0; rv.y = r1; rv.z = r2; rv.w = r3;
        *reinterpret_cast<int4*>(rowptr + base) = rv;
        *reinterpret_cast<int4*>(cursor + base) = rv;
    } else {
        if (base + 0 < NN) { rowptr[base + 0] = r0; cursor[base + 0] = r0; }
        if (base + 1 < NN) { rowptr[base + 1] = r1; cursor[base + 1] = r1; }
        if (base + 2 < NN) { rowptr[base + 2] = r2; cursor[base + 2] = r2; }
    }
    if (blockIdx.x == 0 && t == 0) rowptr[NN] = NE;  // total degree is always E
}

// ---------------- bucket edges by dst: 4 B record {src:16 | u_fp16:16} ----------------
__global__ void fill_kernel(const int* __restrict__ src, const int* __restrict__ dst,
                            const float* __restrict__ attr, int* __restrict__ cursor,
                            unsigned* __restrict__ es, int E) {
    int e = blockIdx.x * blockDim.x + threadIdx.x;
    if (e >= E) return;
    int pos = atomicAdd(&cursor[dst[e]], 1);
    __half uh = __float2half_rn(attr[e]);
    unsigned rec = ((unsigned)src[e] << 16) | (unsigned)__half_as_ushort(uh);
    es[pos] = rec;
}

// ---------------- matmul: lane = output channel, weights VGPR-resident, x via s_load ----------------
// blockIdx.y: 0 -> YabH (half2{a,b} interleaved), 1 -> Z = x@R + B (fp32)
template<int CIN>
__global__ __launch_bounds__(256) void matmulW_kernel(const float* __restrict__ x,
                               const float* __restrict__ W,   // (2, CIN, 64)
                               const float* __restrict__ R,   // (CIN, 64)
                               const float* __restrict__ Bb,  // (64)
                               __half2* __restrict__ YabH,
                               float* __restrict__ Z,
                               int n_nodes) {
    const int lane = threadIdx.x & 63;
    const int wid  = __builtin_amdgcn_readfirstlane(threadIdx.x >> 6);  // wave-uniform
    const int part = blockIdx.y;  // 0: ab, 1: z

    const int CHUNK = 32;
    int n0 = (blockIdx.x * 4 + wid) * CHUNK;
    int n1 = n0 + CHUNK; if (n1 > n_nodes) n1 = n_nodes;

    if (part == 0) {
        float wa[CIN], wb[CIN];
#pragma unroll
        for (int c = 0; c < CIN; ++c) {
            wa[c] = W[c * 64 + lane];
            wb[c] = W[CIN * 64 + c * 64 + lane];
        }
        for (int n = n0; n < n1; ++n) {
            const float* xr = x + (size_t)n * CIN;  // wave-uniform -> s_load
            float acca = 0.f, accb = 0.f;
#pragma unroll
            for (int c = 0; c < CIN; ++c) {
                float xv = xr[c];
                acca = fmaf(xv, wa[c], acca);
                accb = fmaf(xv, wb[c], accb);
            }
            YabH[(size_t)n * 64 + lane] = __floats2half2_rn(acca, accb);
        }
    } else {
        float wr[CIN];
#pragma unroll
        for (int c = 0; c < CIN; ++c) wr[c] = R[c * 64 + lane];
        float bias = Bb[lane];
        for (int n = n0; n < n1; ++n) {
            const float* xr = x + (size_t)n * CIN;
            float acc = 0.f;
#pragma unroll
            for (int c = 0; c < CIN; ++c) acc = fmaf(xr[c], wr[c], acc);
            Z[(size_t)n * 64 + lane] = acc + bias;
        }
    }
}

// ---------------- layer-2 matmul: thread = node, blockIdx.y = {a,b,z} part ----------------
__global__ __launch_bounds__(256) void matmul7_kernel(const float* __restrict__ x,   // (n,64)
                               const float* __restrict__ W,   // (2,64,7)
                               const float* __restrict__ R,   // (64,7)
                               const float* __restrict__ Bb,  // (7)
                               float* __restrict__ Yab7,      // (n,7,2)
                               float* __restrict__ Z,         // (n,7)
                               int n_nodes) {
    int n = blockIdx.x * blockDim.x + threadIdx.x;
    if (n >= n_nodes) return;
    const int part = blockIdx.y;  // 0: a, 1: b, 2: z
    const float* M = (part == 0) ? W : (part == 1) ? (W + 448) : R;
    const float* xr = x + (size_t)n * 64;
    float acc[7];
#pragma unroll
    for (int j = 0; j < 7; ++j) acc[j] = 0.f;
#pragma unroll 2
    for (int c0 = 0; c0 < 64; c0 += 4) {
        float4 xv4 = *reinterpret_cast<const float4*>(xr + c0);
        float xv[4] = { xv4.x, xv4.y, xv4.z, xv4.w };
#pragma unroll
        for (int cc = 0; cc < 4; ++cc) {
            float xv_ = xv[cc];
            int c = c0 + cc;
#pragma unroll
            for (int j = 0; j < 7; ++j) acc[j] = fmaf(xv_, M[c * 7 + j], acc[j]);
        }
    }
    if (part == 0) {
#pragma unroll
        for (int j = 0; j < 7; ++j) Yab7[(size_t)n * 14 + 2 * j] = acc[j];
    } else if (part == 1) {
#pragma unroll
        for (int j = 0; j < 7; ++j) Yab7[(size_t)n * 14 + 2 * j + 1] = acc[j];
    } else {
#pragma unroll
        for (int j = 0; j < 7; ++j) Z[(size_t)n * 7 + j] = acc[j] + Bb[j];
    }
}

// helper: rebuild half2(1-u, u) from the low 16 bits of a record
__device__ inline h2f unpack_u2(unsigned rec) {
    __half uh = __ushort_as_half((unsigned short)(rec & 0xffffu));
    __half one = __ushort_as_half((unsigned short)0x3C00u);
    __half2 p = __halves2half2(__hsub(one, uh), uh);
    return __builtin_bit_cast(h2f, p);
}

// ---------------- gather (H=64) + BN + ELU: one wave per node, fdot2 inner op ----------------
__global__ void gather64_kernel(const int* __restrict__ rowptr,
                                const unsigned* __restrict__ es,
                                const __half2* __restrict__ YabH,
                                const float* __restrict__ Z,
                                const float* __restrict__ G, const float* __restrict__ BE,
                                const float* __restrict__ RM, const float* __restrict__ RV,
                                float* __restrict__ h, int n_nodes) {
    int n = (blockIdx.x * blockDim.x + threadIdx.x) >> 6;
    int lane = threadIdx.x & 63;
    if (n >= n_nodes) return;
    int beg = rowptr[n], end = rowptr[n + 1];
    float acc0 = 0.f, acc1 = 0.f, acc2 = 0.f, acc3 = 0.f;
    float acc4 = 0.f, acc5 = 0.f, acc6 = 0.f, acc7 = 0.f;
    int i = beg;
    for (; i + 7 < end; i += 8) {
        unsigned r0 = es[i],     r1 = es[i + 1], r2 = es[i + 2], r3 = es[i + 3];
        unsigned r4 = es[i + 4], r5 = es[i + 5], r6 = es[i + 6], r7 = es[i + 7];
        __half2 v0 = YabH[(size_t)(r0 >> 16) * 64 + lane];
        __half2 v1 = YabH[(size_t)(r1 >> 16) * 64 + lane];
        __half2 v2 = YabH[(size_t)(r2 >> 16) * 64 + lane];
        __half2 v3 = YabH[(size_t)(r3 >> 16) * 64 + lane];
        __half2 v4 = YabH[(size_t)(r4 >> 16) * 64 + lane];
        __half2 v5 = YabH[(size_t)(r5 >> 16) * 64 + lane];
        __half2 v6 = YabH[(size_t)(r6 >> 16) * 64 + lane];
        __half2 v7 = YabH[(size_t)(r7 >> 16) * 64 + lane];
        acc0 = __builtin_amdgcn_fdot2(__builtin_bit_cast(h2f, v0), unpack_u2(r0), acc0, false);
        acc1 = __builtin_amdgcn_fdot2(__builtin_bit_cast(h2f, v1), unpack_u2(r1), acc1, false);
        acc2 = __builtin_amdgcn_fdot2(__builtin_bit_cast(h2f, v2), unpack_u2(r2), acc2, false);
        acc3 = __builtin_amdgcn_fdot2(__builtin_bit_cast(h2f, v3), unpack_u2(r3), acc3, false);
        acc4 = __builtin_amdgcn_fdot2(__builtin_bit_cast(h2f, v4), unpack_u2(r4), acc4, false);
        acc5 = __builtin_amdgcn_fdot2(__builtin_bit_cast(h2f, v5), unpack_u2(r5), acc5, false);
        acc6 = __builtin_amdgcn_fdot2(__builtin_bit_cast(h2f, v6), unpack_u2(r6), acc6, false);
        acc7 = __builtin_amdgcn_fdot2(__builtin_bit_cast(h2f, v7), unpack_u2(r7), acc7, false);
    }
    for (; i < end; ++i) {
        unsigned r0 = es[i];
        __half2 v0 = YabH[(size_t)(r0 >> 16) * 64 + lane];
        acc0 = __builtin_amdgcn_fdot2(__builtin_bit_cast(h2f, v0), unpack_u2(r0), acc0, false);
    }
    float acc = ((acc0 + acc1) + (acc2 + acc3)) + ((acc4 + acc5) + (acc6 + acc7));
    float degv = (float)(end - beg);
    if (degv < 1.f) degv = 1.f;
    float v = acc / degv + Z[n * 64 + lane];
    v = (v - RM[lane]) * rsqrtf(RV[lane] + EPSV) * G[lane] + BE[lane];
    h[n * 64 + lane] = v > 0.f ? v : expm1f(v);
}

// ---------------- gather (C=7) + log_softmax fused: 8 lanes per node ----------------
__global__ void gather7_final_kernel(const int* __restrict__ rowptr,
                                     const unsigned* __restrict__ es,
                                     const float* __restrict__ Yab7,  // (n,7,2)
                                     const float* __restrict__ Z,
                                     float* __restrict__ out, int n_nodes) {
    int t = blockIdx.x * blockDim.x + threadIdx.x;
    int n = t >> 3;
    int c = t & 7;
    if (n >= n_nodes) return;
    int beg = rowptr[n], end = rowptr[n + 1];
    float acc = 0.f;
    if (c < 7) {
        for (int i = beg; i < end; ++i) {
            unsigned r = es[i];
            float u = __half2float(__ushort_as_half((unsigned short)(r & 0xffffu)));
            float2 ab = *reinterpret_cast<const float2*>(Yab7 + (size_t)(r >> 16) * 14 + 2 * c);
            acc += (1.f - u) * ab.x + u * ab.y;
        }
    }
    float degv = (float)(end - beg);
    if (degv < 1.f) degv = 1.f;
    float v = (c < 7) ? (acc / degv + Z[n * 7 + c]) : -1e30f;
    float m = v;
#pragma unroll
    for (int o = 1; o < 8; o <<= 1) m = fmaxf(m, __shfl_xor(m, o, 8));
    float ex = (c < 7) ? expf(v - m) : 0.f;
    float ssum = ex;
#pragma unroll
    for (int o = 1; o < 8; o <<= 1) ssum += __shfl_xor(ssum, o, 8);
    if (c < 7) out[n * 7 + c] = v - m - logf(ssum);
}

extern "C" void kernel_launch(void* const* d_in, const int* in_sizes, int n_in,
                              void* d_out, int out_size, void* d_ws, size_t ws_size,
                              hipStream_t stream) {
    const float* x    = (const float*)d_in[0];
    const int*   ei   = (const int*)d_in[1];
    const float* attr = (const float*)d_in[2];
    const float* W0 = (const float*)d_in[3];
    const float* R0 = (const float*)d_in[4];
    const float* B0 = (const float*)d_in[5];
    const float* W1 = (const float*)d_in[6];
    const float* R1 = (const float*)d_in[7];
    const float* B1 = (const float*)d_in[8];
    const float* W2 = (const float*)d_in[9];
    const float* R2 = (const float*)d_in[10];
    const float* B2 = (const float*)d_in[11];
    const float* G0  = (const float*)d_in[12];
    const float* BE0 = (const float*)d_in[13];
    const float* RM0 = (const float*)d_in[14];
    const float* RV0 = (const float*)d_in[15];
    const float* G1  = (const float*)d_in[16];
    const float* BE1 = (const float*)d_in[17];
    const float* RM1 = (const float*)d_in[18];
    const float* RV1 = (const float*)d_in[19];

    const int* src = ei;
    const int* dst = ei + NE;
    float* out = (float*)d_out;

    // workspace layout
    char* ws = (char*)d_ws;
    size_t off = 0;
    auto alloc = [&](size_t bytes) { char* p = ws + off; off += (bytes + 255) & ~size_t(255); return p; };
    int*      deg      = (int*)     alloc(NN * sizeof(int));
    int*      rowptr   = (int*)     alloc((NN + 1) * sizeof(int));
    int*      cursor   = (int*)     alloc(NN * sizeof(int));
    int*      blocksum = (int*)     alloc(SCAN_NB * sizeof(int));
    unsigned* es       = (unsigned*)alloc((size_t)NE * sizeof(unsigned));
    __half2*  YabH     = (__half2*) alloc((size_t)NN * 64 * sizeof(__half2));
    float*    Yab7     = (float*)   alloc((size_t)NN * 14 * sizeof(float));
    float*    Z        = (float*)   alloc((size_t)NN * 64 * sizeof(float));
    float*    h        = (float*)   alloc((size_t)NN * 64 * sizeof(float));

    const int B = 256;
    const int gE    = (NE + B - 1) / B;
    const int gN64  = (NN * 64 + B - 1) / B;
    const int gN    = (NN + B - 1) / B;
    const int gN8   = (NN * 8 + B - 1) / B;
    const int gW    = (NN + 4 * 32 - 1) / (4 * 32);  // 4 waves/block, 32 nodes/wave

    // ---- CSR build (once, reused by all 3 layers) ----
    hipMemsetAsync(deg, 0, NN * sizeof(int), stream);
    deg_kernel<<<gE, B, 0, stream>>>(dst, deg, NE);
    scan_phaseA<<<SCAN_NB, 256, 0, stream>>>(deg, blocksum);
    scan_phaseB<<<1, 64, 0, stream>>>(blocksum);
    scan_phaseC<<<SCAN_NB, 256, 0, stream>>>(deg, blocksum, rowptr, cursor);
    fill_kernel<<<gE, B, 0, stream>>>(src, dst, attr, cursor, es, NE);

    // ---- layer 0: F_IN=32 -> H=64 ----
    matmulW_kernel<32><<<dim3(gW, 2), B, 0, stream>>>(x, W0, R0, B0, YabH, Z, NN);
    gather64_kernel<<<gN64, B, 0, stream>>>(rowptr, es, YabH, Z, G0, BE0, RM0, RV0, h, NN);

    // ---- layer 1: H=64 -> H=64 ----
    matmulW_kernel<64><<<dim3(gW, 2), B, 0, stream>>>(h, W1, R1, B1, YabH, Z, NN);
    gather64_kernel<<<gN64, B, 0, stream>>>(rowptr, es, YabH, Z, G1, BE1, RM1, RV1, h, NN);

    // ---- layer 2: H=64 -> C=7, then log_softmax ----
    matmul7_kernel<<<dim3(gN, 3), B, 0, stream>>>(h, W2, R2, B2, Yab7, Z, NN);
    gather7_final_kernel<<<gN8, B, 0, stream>>>(rowptr, es, Yab7, Z, out, NN);
}

// Round 11
// 313.419 us; speedup vs baseline: 1.1819x; 1.1819x over previous
//
#include <hip/hip_runtime.h>
#include <hip/hip_fp16.h>
#include <math.h>

#define NN 50000
#define NE 800000
#define EPSV 1e-5f
#define BSHIFT 7
#define BSIZE 128
#define NB 391   // ceil(NN / 128)

typedef _Float16 h2f __attribute__((ext_vector_type(2)));

// ---------------- CSR build, phase A: coarse bucket histogram (LDS-aggregated) ----------------
__global__ __launch_bounds__(256) void histA_kernel(const int* __restrict__ dst,
                                                    int* __restrict__ bcount, int E) {
    __shared__ int hist[NB];
    for (int i = threadIdx.x; i < NB; i += blockDim.x) hist[i] = 0;
    __syncthreads();
    int chunk = (E + gridDim.x - 1) / gridDim.x;
    int e0 = blockIdx.x * chunk;
    int e1 = e0 + chunk; if (e1 > E) e1 = E;
    for (int e = e0 + threadIdx.x; e < e1; e += blockDim.x)
        atomicAdd(&hist[dst[e] >> BSHIFT], 1);
    __syncthreads();
    for (int i = threadIdx.x; i < NB; i += blockDim.x)
        if (hist[i]) atomicAdd(&bcount[i], hist[i]);
}

// ---------------- phase B0: exclusive scan of bucket counts -> bbase, bcursor ----------------
__global__ __launch_bounds__(512) void bscan_kernel(const int* __restrict__ bcount,
                                                    int* __restrict__ bbase,
                                                    int* __restrict__ bcursor) {
    __shared__ int wsum[8];
    int t = threadIdx.x;  // 0..511
    int v = (t < NB) ? bcount[t] : 0;
    int incl = v;
#pragma unroll
    for (int o = 1; o < 64; o <<= 1) {
        int nv = __shfl_up(incl, o, 64);
        if ((t & 63) >= o) incl += nv;
    }
    if ((t & 63) == 63) wsum[t >> 6] = incl;
    __syncthreads();
    if (t == 0) {
        int r = 0;
#pragma unroll
        for (int i = 0; i < 8; ++i) { int x = wsum[i]; wsum[i] = r; r += x; }
    }
    __syncthreads();
    int excl = incl - v + wsum[t >> 6];
    if (t <= NB) bbase[t] = excl;     // bbase[NB] == NE
    if (t < NB)  bcursor[t] = excl;
}

// ---------------- phase B: bin edges into bucket-contiguous regions (bulk claims) ----------------
__global__ __launch_bounds__(256) void binB_kernel(const int* __restrict__ src,
                                                   const int* __restrict__ dst,
                                                   const float* __restrict__ attr,
                                                   int* __restrict__ bcursor,
                                                   unsigned* __restrict__ es1su,
                                                   unsigned char* __restrict__ es1dl, int E) {
    __shared__ int hist[NB];
    __shared__ int base[NB];
    for (int i = threadIdx.x; i < NB; i += blockDim.x) hist[i] = 0;
    __syncthreads();
    int chunk = (E + gridDim.x - 1) / gridDim.x;
    int e0 = blockIdx.x * chunk;
    int e1 = e0 + chunk; if (e1 > E) e1 = E;
    // pass 1: local counts
    for (int e = e0 + threadIdx.x; e < e1; e += blockDim.x)
        atomicAdd(&hist[dst[e] >> BSHIFT], 1);
    __syncthreads();
    // bulk claim per bucket, reset local counter
    for (int i = threadIdx.x; i < NB; i += blockDim.x) {
        int c = hist[i];
        base[i] = c ? atomicAdd(&bcursor[i], c) : 0;
        hist[i] = 0;
    }
    __syncthreads();
    // pass 2: place
    for (int e = e0 + threadIdx.x; e < e1; e += blockDim.x) {
        int d = dst[e];
        int b = d >> BSHIFT;
        int slot = base[b] + atomicAdd(&hist[b], 1);
        __half uh = __float2half_rn(attr[e]);
        es1su[slot] = ((unsigned)src[e] << 16) | (unsigned)__half_as_ushort(uh);
        es1dl[slot] = (unsigned char)(d & (BSIZE - 1));
    }
}

// ---------------- phase C: exact placement within bucket + rowptr (LDS atomics only) ----------------
__global__ __launch_bounds__(256) void placeC_kernel(const int* __restrict__ bbase,
                                                     const unsigned* __restrict__ es1su,
                                                     const unsigned char* __restrict__ es1dl,
                                                     int* __restrict__ rowptr,
                                                     unsigned* __restrict__ es) {
    __shared__ int hist[BSIZE];
    __shared__ int stmp[BSIZE];
    __shared__ int cur[BSIZE];
    int b = blockIdx.x;
    int t = threadIdx.x;
    int bs = bbase[b], be = bbase[b + 1];
    if (t < BSIZE) hist[t] = 0;
    __syncthreads();
    for (int i = bs + t; i < be; i += blockDim.x)
        atomicAdd(&hist[es1dl[i]], 1);
    __syncthreads();
    if (t < BSIZE) {
        int v = hist[t];
        int incl = v;
#pragma unroll
        for (int o = 1; o < 64; o <<= 1) {
            int nv = __shfl_up(incl, o, 64);
            if ((t & 63) >= o) incl += nv;
        }
        stmp[t] = incl;
    }
    __syncthreads();
    if (t < BSIZE) {
        int excl = stmp[t] - hist[t] + ((t >= 64) ? stmp[63] : 0);
        cur[t] = excl;
        int node = b * BSIZE + t;
        if (node < NN) rowptr[node] = bs + excl;
    }
    if (b == NB - 1 && t == 0) rowptr[NN] = NE;
    __syncthreads();
    for (int i = bs + t; i < be; i += blockDim.x) {
        unsigned r = es1su[i];
        int dl = es1dl[i];
        int slot = bs + atomicAdd(&cur[dl], 1);
        es[slot] = r;
    }
}

// ---------------- matmul: lane = output channel, weights VGPR-resident, x via s_load ----------------
// blockIdx.y: 0 -> YabH (half2{a,b} interleaved), 1 -> Z = x@R + B (fp32)
template<int CIN>
__global__ __launch_bounds__(256) void matmulW_kernel(const float* __restrict__ x,
                               const float* __restrict__ W,   // (2, CIN, 64)
                               const float* __restrict__ R,   // (CIN, 64)
                               const float* __restrict__ Bb,  // (64)
                               __half2* __restrict__ YabH,
                               float* __restrict__ Z,
                               int n_nodes) {
    const int lane = threadIdx.x & 63;
    const int wid  = __builtin_amdgcn_readfirstlane(threadIdx.x >> 6);  // wave-uniform
    const int part = blockIdx.y;  // 0: ab, 1: z

    const int CHUNK = 32;
    int n0 = (blockIdx.x * 4 + wid) * CHUNK;
    int n1 = n0 + CHUNK; if (n1 > n_nodes) n1 = n_nodes;

    if (part == 0) {
        float wa[CIN], wb[CIN];
#pragma unroll
        for (int c = 0; c < CIN; ++c) {
            wa[c] = W[c * 64 + lane];
            wb[c] = W[CIN * 64 + c * 64 + lane];
        }
        for (int n = n0; n < n1; ++n) {
            const float* xr = x + (size_t)n * CIN;  // wave-uniform -> s_load
            float acca = 0.f, accb = 0.f;
#pragma unroll
            for (int c = 0; c < CIN; ++c) {
                float xv = xr[c];
                acca = fmaf(xv, wa[c], acca);
                accb = fmaf(xv, wb[c], accb);
            }
            YabH[(size_t)n * 64 + lane] = __floats2half2_rn(acca, accb);
        }
    } else {
        float wr[CIN];
#pragma unroll
        for (int c = 0; c < CIN; ++c) wr[c] = R[c * 64 + lane];
        float bias = Bb[lane];
        for (int n = n0; n < n1; ++n) {
            const float* xr = x + (size_t)n * CIN;
            float acc = 0.f;
#pragma unroll
            for (int c = 0; c < CIN; ++c) acc = fmaf(xr[c], wr[c], acc);
            Z[(size_t)n * 64 + lane] = acc + bias;
        }
    }
}

// ---------------- layer-2 matmul: thread = node, blockIdx.y = {a,b,z} part ----------------
__global__ __launch_bounds__(256) void matmul7_kernel(const float* __restrict__ x,   // (n,64)
                               const float* __restrict__ W,   // (2,64,7)
                               const float* __restrict__ R,   // (64,7)
                               const float* __restrict__ Bb,  // (7)
                               float* __restrict__ Yab7,      // (n,7,2)
                               float* __restrict__ Z,         // (n,7)
                               int n_nodes) {
    int n = blockIdx.x * blockDim.x + threadIdx.x;
    if (n >= n_nodes) return;
    const int part = blockIdx.y;  // 0: a, 1: b, 2: z
    const float* M = (part == 0) ? W : (part == 1) ? (W + 448) : R;
    const float* xr = x + (size_t)n * 64;
    float acc[7];
#pragma unroll
    for (int j = 0; j < 7; ++j) acc[j] = 0.f;
#pragma unroll 2
    for (int c0 = 0; c0 < 64; c0 += 4) {
        float4 xv4 = *reinterpret_cast<const float4*>(xr + c0);
        float xv[4] = { xv4.x, xv4.y, xv4.z, xv4.w };
#pragma unroll
        for (int cc = 0; cc < 4; ++cc) {
            float xv_ = xv[cc];
            int c = c0 + cc;
#pragma unroll
            for (int j = 0; j < 7; ++j) acc[j] = fmaf(xv_, M[c * 7 + j], acc[j]);
        }
    }
    if (part == 0) {
#pragma unroll
        for (int j = 0; j < 7; ++j) Yab7[(size_t)n * 14 + 2 * j] = acc[j];
    } else if (part == 1) {
#pragma unroll
        for (int j = 0; j < 7; ++j) Yab7[(size_t)n * 14 + 2 * j + 1] = acc[j];
    } else {
#pragma unroll
        for (int j = 0; j < 7; ++j) Z[(size_t)n * 7 + j] = acc[j] + Bb[j];
    }
}

// helper: rebuild half2(1-u, u) from the low 16 bits of a record
__device__ inline h2f unpack_u2(unsigned rec) {
    __half uh = __ushort_as_half((unsigned short)(rec & 0xffffu));
    __half one = __ushort_as_half((unsigned short)0x3C00u);
    __half2 p = __halves2half2(__hsub(one, uh), uh);
    return __builtin_bit_cast(h2f, p);
}

// ---------------- gather (H=64) + BN + ELU: one wave per node, fdot2 inner op ----------------
__global__ void gather64_kernel(const int* __restrict__ rowptr,
                                const unsigned* __restrict__ es,
                                const __half2* __restrict__ YabH,
                                const float* __restrict__ Z,
                                const float* __restrict__ G, const float* __restrict__ BE,
                                const float* __restrict__ RM, const float* __restrict__ RV,
                                float* __restrict__ h, int n_nodes) {
    int n = (blockIdx.x * blockDim.x + threadIdx.x) >> 6;
    int lane = threadIdx.x & 63;
    if (n >= n_nodes) return;
    int beg = rowptr[n], end = rowptr[n + 1];
    float acc0 = 0.f, acc1 = 0.f, acc2 = 0.f, acc3 = 0.f;
    float acc4 = 0.f, acc5 = 0.f, acc6 = 0.f, acc7 = 0.f;
    int i = beg;
    for (; i + 7 < end; i += 8) {
        unsigned r0 = es[i],     r1 = es[i + 1], r2 = es[i + 2], r3 = es[i + 3];
        unsigned r4 = es[i + 4], r5 = es[i + 5], r6 = es[i + 6], r7 = es[i + 7];
        __half2 v0 = YabH[(size_t)(r0 >> 16) * 64 + lane];
        __half2 v1 = YabH[(size_t)(r1 >> 16) * 64 + lane];
        __half2 v2 = YabH[(size_t)(r2 >> 16) * 64 + lane];
        __half2 v3 = YabH[(size_t)(r3 >> 16) * 64 + lane];
        __half2 v4 = YabH[(size_t)(r4 >> 16) * 64 + lane];
        __half2 v5 = YabH[(size_t)(r5 >> 16) * 64 + lane];
        __half2 v6 = YabH[(size_t)(r6 >> 16) * 64 + lane];
        __half2 v7 = YabH[(size_t)(r7 >> 16) * 64 + lane];
        acc0 = __builtin_amdgcn_fdot2(__builtin_bit_cast(h2f, v0), unpack_u2(r0), acc0, false);
        acc1 = __builtin_amdgcn_fdot2(__builtin_bit_cast(h2f, v1), unpack_u2(r1), acc1, false);
        acc2 = __builtin_amdgcn_fdot2(__builtin_bit_cast(h2f, v2), unpack_u2(r2), acc2, false);
        acc3 = __builtin_amdgcn_fdot2(__builtin_bit_cast(h2f, v3), unpack_u2(r3), acc3, false);
        acc4 = __builtin_amdgcn_fdot2(__builtin_bit_cast(h2f, v4), unpack_u2(r4), acc4, false);
        acc5 = __builtin_amdgcn_fdot2(__builtin_bit_cast(h2f, v5), unpack_u2(r5), acc5, false);
        acc6 = __builtin_amdgcn_fdot2(__builtin_bit_cast(h2f, v6), unpack_u2(r6), acc6, false);
        acc7 = __builtin_amdgcn_fdot2(__builtin_bit_cast(h2f, v7), unpack_u2(r7), acc7, false);
    }
    for (; i < end; ++i) {
        unsigned r0 = es[i];
        __half2 v0 = YabH[(size_t)(r0 >> 16) * 64 + lane];
        acc0 = __builtin_amdgcn_fdot2(__builtin_bit_cast(h2f, v0), unpack_u2(r0), acc0, false);
    }
    float acc = ((acc0 + acc1) + (acc2 + acc3)) + ((acc4 + acc5) + (acc6 + acc7));
    float degv = (float)(end - beg);
    if (degv < 1.f) degv = 1.f;
    float v = acc / degv + Z[n * 64 + lane];
    v = (v - RM[lane]) * rsqrtf(RV[lane] + EPSV) * G[lane] + BE[lane];
    h[n * 64 + lane] = v > 0.f ? v : expm1f(v);
}

// ---------------- gather (C=7) + log_softmax fused: 8 lanes per node ----------------
__global__ void gather7_final_kernel(const int* __restrict__ rowptr,
                                     const unsigned* __restrict__ es,
                                     const float* __restrict__ Yab7,  // (n,7,2)
                                     const float* __restrict__ Z,
                                     float* __restrict__ out, int n_nodes) {
    int t = blockIdx.x * blockDim.x + threadIdx.x;
    int n = t >> 3;
    int c = t & 7;
    if (n >= n_nodes) return;
    int beg = rowptr[n], end = rowptr[n + 1];
    float acc = 0.f;
    if (c < 7) {
        for (int i = beg; i < end; ++i) {
            unsigned r = es[i];
            float u = __half2float(__ushort_as_half((unsigned short)(r & 0xffffu)));
            float2 ab = *reinterpret_cast<const float2*>(Yab7 + (size_t)(r >> 16) * 14 + 2 * c);
            acc += (1.f - u) * ab.x + u * ab.y;
        }
    }
    float degv = (float)(end - beg);
    if (degv < 1.f) degv = 1.f;
    float v = (c < 7) ? (acc / degv + Z[n * 7 + c]) : -1e30f;
    float m = v;
#pragma unroll
    for (int o = 1; o < 8; o <<= 1) m = fmaxf(m, __shfl_xor(m, o, 8));
    float ex = (c < 7) ? expf(v - m) : 0.f;
    float ssum = ex;
#pragma unroll
    for (int o = 1; o < 8; o <<= 1) ssum += __shfl_xor(ssum, o, 8);
    if (c < 7) out[n * 7 + c] = v - m - logf(ssum);
}

extern "C" void kernel_launch(void* const* d_in, const int* in_sizes, int n_in,
                              void* d_out, int out_size, void* d_ws, size_t ws_size,
                              hipStream_t stream) {
    const float* x    = (const float*)d_in[0];
    const int*   ei   = (const int*)d_in[1];
    const float* attr = (const float*)d_in[2];
    const float* W0 = (const float*)d_in[3];
    const float* R0 = (const float*)d_in[4];
    const float* B0 = (const float*)d_in[5];
    const float* W1 = (const float*)d_in[6];
    const float* R1 = (const float*)d_in[7];
    const float* B1 = (const float*)d_in[8];
    const float* W2 = (const float*)d_in[9];
    const float* R2 = (const float*)d_in[10];
    const float* B2 = (const float*)d_in[11];
    const float* G0  = (const float*)d_in[12];
    const float* BE0 = (const float*)d_in[13];
    const float* RM0 = (const float*)d_in[14];
    const float* RV0 = (const float*)d_in[15];
    const float* G1  = (const float*)d_in[16];
    const float* BE1 = (const float*)d_in[17];
    const float* RM1 = (const float*)d_in[18];
    const float* RV1 = (const float*)d_in[19];

    const int* src = ei;
    const int* dst = ei + NE;
    float* out = (float*)d_out;

    // workspace layout
    char* ws = (char*)d_ws;
    size_t off = 0;
    auto alloc = [&](size_t bytes) { char* p = ws + off; off += (bytes + 255) & ~size_t(255); return p; };
    int*           bcount   = (int*)          alloc(NB * sizeof(int));
    int*           bbase    = (int*)          alloc((NB + 1) * sizeof(int));
    int*           bcursor  = (int*)          alloc(NB * sizeof(int));
    int*           rowptr   = (int*)          alloc((NN + 1) * sizeof(int));
    unsigned*      es1su    = (unsigned*)     alloc((size_t)NE * sizeof(unsigned));
    unsigned char* es1dl    = (unsigned char*)alloc((size_t)NE * sizeof(unsigned char));
    unsigned*      es       = (unsigned*)     alloc((size_t)NE * sizeof(unsigned));
    __half2*       YabH     = (__half2*)      alloc((size_t)NN * 64 * sizeof(__half2));
    float*         Yab7     = (float*)        alloc((size_t)NN * 14 * sizeof(float));
    float*         Z        = (float*)        alloc((size_t)NN * 64 * sizeof(float));
    float*         h        = (float*)        alloc((size_t)NN * 64 * sizeof(float));

    const int B = 256;
    const int gN64  = (NN * 64 + B - 1) / B;
    const int gN    = (NN + B - 1) / B;
    const int gN8   = (NN * 8 + B - 1) / B;
    const int gW    = (NN + 4 * 32 - 1) / (4 * 32);  // 4 waves/block, 32 nodes/wave

    // ---- CSR build via bucketed counting sort (once, reused by all 3 layers) ----
    hipMemsetAsync(bcount, 0, NB * sizeof(int), stream);
    histA_kernel<<<NB, B, 0, stream>>>(dst, bcount, NE);
    bscan_kernel<<<1, 512, 0, stream>>>(bcount, bbase, bcursor);
    binB_kernel<<<NB, B, 0, stream>>>(src, dst, attr, bcursor, es1su, es1dl, NE);
    placeC_kernel<<<NB, B, 0, stream>>>(bbase, es1su, es1dl, rowptr, es);

    // ---- layer 0: F_IN=32 -> H=64 ----
    matmulW_kernel<32><<<dim3(gW, 2), B, 0, stream>>>(x, W0, R0, B0, YabH, Z, NN);
    gather64_kernel<<<gN64, B, 0, stream>>>(rowptr, es, YabH, Z, G0, BE0, RM0, RV0, h, NN);

    // ---- layer 1: H=64 -> H=64 ----
    matmulW_kernel<64><<<dim3(gW, 2), B, 0, stream>>>(h, W1, R1, B1, YabH, Z, NN);
    gather64_kernel<<<gN64, B, 0, stream>>>(rowptr, es, YabH, Z, G1, BE1, RM1, RV1, h, NN);

    // ---- layer 2: H=64 -> C=7, then log_softmax ----
    matmul7_kernel<<<dim3(gN, 3), B, 0, stream>>>(h, W2, R2, B2, Yab7, Z, NN);
    gather7_final_kernel<<<gN8, B, 0, stream>>>(rowptr, es, Yab7, Z, out, NN);
}

// Round 12
// 275.846 us; speedup vs baseline: 1.3429x; 1.1362x over previous
//
#include <hip/hip_runtime.h>
#include <hip/hip_fp16.h>
#include <math.h>

#define NN 50000
#define NE 800000
#define EPSV 1e-5f
#define BSHIFT 7
#define BSIZE 128
#define NB 391   // ceil(NN / 128)

typedef _Float16 h2f  __attribute__((ext_vector_type(2)));
typedef _Float16 f16x8 __attribute__((ext_vector_type(8)));
typedef float    f32x4 __attribute__((ext_vector_type(4)));

// ---------------- CSR build, phase A: coarse bucket histogram (LDS-aggregated) ----------------
__global__ __launch_bounds__(256) void histA_kernel(const int* __restrict__ dst,
                                                    int* __restrict__ bcount, int E) {
    __shared__ int hist[NB];
    for (int i = threadIdx.x; i < NB; i += blockDim.x) hist[i] = 0;
    __syncthreads();
    int chunk = (E + gridDim.x - 1) / gridDim.x;
    int e0 = blockIdx.x * chunk;
    int e1 = e0 + chunk; if (e1 > E) e1 = E;
    for (int e = e0 + threadIdx.x; e < e1; e += blockDim.x)
        atomicAdd(&hist[dst[e] >> BSHIFT], 1);
    __syncthreads();
    for (int i = threadIdx.x; i < NB; i += blockDim.x)
        if (hist[i]) atomicAdd(&bcount[i], hist[i]);
}

// ---------------- phase B0: exclusive scan of bucket counts -> bbase, bcursor ----------------
__global__ __launch_bounds__(512) void bscan_kernel(const int* __restrict__ bcount,
                                                    int* __restrict__ bbase,
                                                    int* __restrict__ bcursor) {
    __shared__ int wsum[8];
    int t = threadIdx.x;  // 0..511
    int v = (t < NB) ? bcount[t] : 0;
    int incl = v;
#pragma unroll
    for (int o = 1; o < 64; o <<= 1) {
        int nv = __shfl_up(incl, o, 64);
        if ((t & 63) >= o) incl += nv;
    }
    if ((t & 63) == 63) wsum[t >> 6] = incl;
    __syncthreads();
    if (t == 0) {
        int r = 0;
#pragma unroll
        for (int i = 0; i < 8; ++i) { int x = wsum[i]; wsum[i] = r; r += x; }
    }
    __syncthreads();
    int excl = incl - v + wsum[t >> 6];
    if (t <= NB) bbase[t] = excl;     // bbase[NB] == NE
    if (t < NB)  bcursor[t] = excl;
}

// ---------------- phase B: bin edges into bucket-contiguous regions (bulk claims) ----------------
__global__ __launch_bounds__(256) void binB_kernel(const int* __restrict__ src,
                                                   const int* __restrict__ dst,
                                                   const float* __restrict__ attr,
                                                   int* __restrict__ bcursor,
                                                   unsigned* __restrict__ es1su,
                                                   unsigned char* __restrict__ es1dl, int E) {
    __shared__ int hist[NB];
    __shared__ int base[NB];
    for (int i = threadIdx.x; i < NB; i += blockDim.x) hist[i] = 0;
    __syncthreads();
    int chunk = (E + gridDim.x - 1) / gridDim.x;
    int e0 = blockIdx.x * chunk;
    int e1 = e0 + chunk; if (e1 > E) e1 = E;
    for (int e = e0 + threadIdx.x; e < e1; e += blockDim.x)
        atomicAdd(&hist[dst[e] >> BSHIFT], 1);
    __syncthreads();
    for (int i = threadIdx.x; i < NB; i += blockDim.x) {
        int c = hist[i];
        base[i] = c ? atomicAdd(&bcursor[i], c) : 0;
        hist[i] = 0;
    }
    __syncthreads();
    for (int e = e0 + threadIdx.x; e < e1; e += blockDim.x) {
        int d = dst[e];
        int b = d >> BSHIFT;
        int slot = base[b] + atomicAdd(&hist[b], 1);
        __half uh = __float2half_rn(attr[e]);
        es1su[slot] = ((unsigned)src[e] << 16) | (unsigned)__half_as_ushort(uh);
        es1dl[slot] = (unsigned char)(d & (BSIZE - 1));
    }
}

// ---------------- phase C: exact placement within bucket + rowptr (LDS atomics only) ----------------
__global__ __launch_bounds__(256) void placeC_kernel(const int* __restrict__ bbase,
                                                     const unsigned* __restrict__ es1su,
                                                     const unsigned char* __restrict__ es1dl,
                                                     int* __restrict__ rowptr,
                                                     unsigned* __restrict__ es) {
    __shared__ int hist[BSIZE];
    __shared__ int stmp[BSIZE];
    __shared__ int cur[BSIZE];
    int b = blockIdx.x;
    int t = threadIdx.x;
    int bs = bbase[b], be = bbase[b + 1];
    if (t < BSIZE) hist[t] = 0;
    __syncthreads();
    for (int i = bs + t; i < be; i += blockDim.x)
        atomicAdd(&hist[es1dl[i]], 1);
    __syncthreads();
    if (t < BSIZE) {
        int v = hist[t];
        int incl = v;
#pragma unroll
        for (int o = 1; o < 64; o <<= 1) {
            int nv = __shfl_up(incl, o, 64);
            if ((t & 63) >= o) incl += nv;
        }
        stmp[t] = incl;
    }
    __syncthreads();
    if (t < BSIZE) {
        int excl = stmp[t] - hist[t] + ((t >= 64) ? stmp[63] : 0);
        cur[t] = excl;
        int node = b * BSIZE + t;
        if (node < NN) rowptr[node] = bs + excl;
    }
    if (b == NB - 1 && t == 0) rowptr[NN] = NE;
    __syncthreads();
    for (int i = bs + t; i < be; i += blockDim.x) {
        unsigned r = es1su[i];
        int dl = es1dl[i];
        int slot = bs + atomicAdd(&cur[dl], 1);
        es[slot] = r;
    }
}

// ---------------- weight prep: pre-swizzled fp16 B-fragments for MFMA ----------------
// B matrix (CIN x 192) = [Wa | Wb | R]. Fragment layout per (ks, nt):
// Bfrag[((ks*12+nt)*64 + lane)*8 + j] = B[ks*32 + (lane>>4)*8 + j][nt*16 + (lane&15)]
template<int CIN>
__global__ void prepB_kernel(const float* __restrict__ W, const float* __restrict__ R,
                             __half* __restrict__ Bfrag) {
    int lane = threadIdx.x;       // 64 threads
    int ksnt = blockIdx.x;        // (CIN/32)*12 blocks
    int ks = ksnt / 12, nt = ksnt - ks * 12;
    int n = nt * 16 + (lane & 15);
    _Float16 vals[8];
#pragma unroll
    for (int j = 0; j < 8; ++j) {
        int k = ks * 32 + ((lane >> 4) << 3) + j;
        float v;
        if (n < 64)       v = W[k * 64 + n];
        else if (n < 128) v = W[CIN * 64 + k * 64 + (n - 64)];
        else              v = R[k * 64 + (n - 128)];
        vals[j] = (_Float16)v;
    }
    *reinterpret_cast<f16x8*>(Bfrag + ((size_t)(ksnt * 64 + lane)) * 8) =
        *reinterpret_cast<f16x8*>(vals);
}

// ---------------- MFMA GEMM: [YabH | Z] = x @ [Wa|Wb|R] (+bias on Z) ----------------
// wave = one 16-row M-tile; 12 N-tiles of 16 cols (0-63 a, 64-127 b, 128-191 z)
template<int CIN>
__global__ __launch_bounds__(256) void gemm_kernel(const float* __restrict__ x,
                               const __half* __restrict__ Bfrag,
                               const float* __restrict__ Bb,   // (64) bias for Z
                               __half2* __restrict__ YabH,
                               float* __restrict__ Z,
                               int n_nodes) {
    const int lane = threadIdx.x & 63;
    const int wid  = threadIdx.x >> 6;
    int m0 = (blockIdx.x * 4 + wid) * 16;
    if (m0 >= n_nodes) return;
    const int KS = CIN / 32;

    f32x4 acc[12];
#pragma unroll
    for (int i = 0; i < 12; ++i) acc[i] = (f32x4){0.f, 0.f, 0.f, 0.f};

    const int arow = m0 + (lane & 15);
    const int koff = ((lane >> 4) << 3);
    const f16x8* bf = reinterpret_cast<const f16x8*>(Bfrag);
#pragma unroll
    for (int ks = 0; ks < KS; ++ks) {
        const float* ap = x + (size_t)arow * CIN + ks * 32 + koff;
        float4 a0 = *reinterpret_cast<const float4*>(ap);
        float4 a1 = *reinterpret_cast<const float4*>(ap + 4);
        f16x8 av;
        av[0] = (_Float16)a0.x; av[1] = (_Float16)a0.y;
        av[2] = (_Float16)a0.z; av[3] = (_Float16)a0.w;
        av[4] = (_Float16)a1.x; av[5] = (_Float16)a1.y;
        av[6] = (_Float16)a1.z; av[7] = (_Float16)a1.w;
#pragma unroll
        for (int nt = 0; nt < 12; ++nt) {
            f16x8 bv = bf[(ks * 12 + nt) * 64 + lane];
            acc[nt] = __builtin_amdgcn_mfma_f32_16x16x32_f16(av, bv, acc[nt], 0, 0, 0);
        }
    }

    // epilogue: C/D layout col=lane&15, row=(lane>>4)*4+r
    const int c_lo  = lane & 15;
    const int rbase = ((lane >> 4) << 2);
#pragma unroll
    for (int r = 0; r < 4; ++r) {
        int row = m0 + rbase + r;
#pragma unroll
        for (int nt = 0; nt < 4; ++nt) {
            int c = nt * 16 + c_lo;
            YabH[(size_t)row * 64 + c] = __floats2half2_rn(acc[nt][r], acc[nt + 4][r]);
        }
#pragma unroll
        for (int nt = 8; nt < 12; ++nt) {
            int c = (nt - 8) * 16 + c_lo;
            Z[(size_t)row * 64 + c] = acc[nt][r] + Bb[c];
        }
    }
}

// ---------------- layer-2 matmul: thread = node, blockIdx.y = {a,b,z} part ----------------
__global__ __launch_bounds__(256) void matmul7_kernel(const float* __restrict__ x,   // (n,64)
                               const float* __restrict__ W,   // (2,64,7)
                               const float* __restrict__ R,   // (64,7)
                               const float* __restrict__ Bb,  // (7)
                               float* __restrict__ Yab7,      // (n,7,2)
                               float* __restrict__ Z,         // (n,7)
                               int n_nodes) {
    int n = blockIdx.x * blockDim.x + threadIdx.x;
    if (n >= n_nodes) return;
    const int part = blockIdx.y;  // 0: a, 1: b, 2: z
    const float* M = (part == 0) ? W : (part == 1) ? (W + 448) : R;
    const float* xr = x + (size_t)n * 64;
    float acc[7];
#pragma unroll
    for (int j = 0; j < 7; ++j) acc[j] = 0.f;
#pragma unroll 2
    for (int c0 = 0; c0 < 64; c0 += 4) {
        float4 xv4 = *reinterpret_cast<const float4*>(xr + c0);
        float xv[4] = { xv4.x, xv4.y, xv4.z, xv4.w };
#pragma unroll
        for (int cc = 0; cc < 4; ++cc) {
            float xv_ = xv[cc];
            int c = c0 + cc;
#pragma unroll
            for (int j = 0; j < 7; ++j) acc[j] = fmaf(xv_, M[c * 7 + j], acc[j]);
        }
    }
    if (part == 0) {
#pragma unroll
        for (int j = 0; j < 7; ++j) Yab7[(size_t)n * 14 + 2 * j] = acc[j];
    } else if (part == 1) {
#pragma unroll
        for (int j = 0; j < 7; ++j) Yab7[(size_t)n * 14 + 2 * j + 1] = acc[j];
    } else {
#pragma unroll
        for (int j = 0; j < 7; ++j) Z[(size_t)n * 7 + j] = acc[j] + Bb[j];
    }
}

// helper: rebuild half2(1-u, u) from the low 16 bits of a record
__device__ inline h2f unpack_u2(unsigned rec) {
    __half uh = __ushort_as_half((unsigned short)(rec & 0xffffu));
    __half one = __ushort_as_half((unsigned short)0x3C00u);
    __half2 p = __halves2half2(__hsub(one, uh), uh);
    return __builtin_bit_cast(h2f, p);
}

// ---------------- gather (H=64) + BN + ELU: one wave per node, fdot2 inner op ----------------
__global__ void gather64_kernel(const int* __restrict__ rowptr,
                                const unsigned* __restrict__ es,
                                const __half2* __restrict__ YabH,
                                const float* __restrict__ Z,
                                const float* __restrict__ G, const float* __restrict__ BE,
                                const float* __restrict__ RM, const float* __restrict__ RV,
                                float* __restrict__ h, int n_nodes) {
    int n = (blockIdx.x * blockDim.x + threadIdx.x) >> 6;
    int lane = threadIdx.x & 63;
    if (n >= n_nodes) return;
    int beg = rowptr[n], end = rowptr[n + 1];
    float acc0 = 0.f, acc1 = 0.f, acc2 = 0.f, acc3 = 0.f;
    float acc4 = 0.f, acc5 = 0.f, acc6 = 0.f, acc7 = 0.f;
    int i = beg;
    for (; i + 7 < end; i += 8) {
        unsigned r0 = es[i],     r1 = es[i + 1], r2 = es[i + 2], r3 = es[i + 3];
        unsigned r4 = es[i + 4], r5 = es[i + 5], r6 = es[i + 6], r7 = es[i + 7];
        __half2 v0 = YabH[(size_t)(r0 >> 16) * 64 + lane];
        __half2 v1 = YabH[(size_t)(r1 >> 16) * 64 + lane];
        __half2 v2 = YabH[(size_t)(r2 >> 16) * 64 + lane];
        __half2 v3 = YabH[(size_t)(r3 >> 16) * 64 + lane];
        __half2 v4 = YabH[(size_t)(r4 >> 16) * 64 + lane];
        __half2 v5 = YabH[(size_t)(r5 >> 16) * 64 + lane];
        __half2 v6 = YabH[(size_t)(r6 >> 16) * 64 + lane];
        __half2 v7 = YabH[(size_t)(r7 >> 16) * 64 + lane];
        acc0 = __builtin_amdgcn_fdot2(__builtin_bit_cast(h2f, v0), unpack_u2(r0), acc0, false);
        acc1 = __builtin_amdgcn_fdot2(__builtin_bit_cast(h2f, v1), unpack_u2(r1), acc1, false);
        acc2 = __builtin_amdgcn_fdot2(__builtin_bit_cast(h2f, v2), unpack_u2(r2), acc2, false);
        acc3 = __builtin_amdgcn_fdot2(__builtin_bit_cast(h2f, v3), unpack_u2(r3), acc3, false);
        acc4 = __builtin_amdgcn_fdot2(__builtin_bit_cast(h2f, v4), unpack_u2(r4), acc4, false);
        acc5 = __builtin_amdgcn_fdot2(__builtin_bit_cast(h2f, v5), unpack_u2(r5), acc5, false);
        acc6 = __builtin_amdgcn_fdot2(__builtin_bit_cast(h2f, v6), unpack_u2(r6), acc6, false);
        acc7 = __builtin_amdgcn_fdot2(__builtin_bit_cast(h2f, v7), unpack_u2(r7), acc7, false);
    }
    for (; i < end; ++i) {
        unsigned r0 = es[i];
        __half2 v0 = YabH[(size_t)(r0 >> 16) * 64 + lane];
        acc0 = __builtin_amdgcn_fdot2(__builtin_bit_cast(h2f, v0), unpack_u2(r0), acc0, false);
    }
    float acc = ((acc0 + acc1) + (acc2 + acc3)) + ((acc4 + acc5) + (acc6 + acc7));
    float degv = (float)(end - beg);
    if (degv < 1.f) degv = 1.f;
    float v = acc / degv + Z[n * 64 + lane];
    v = (v - RM[lane]) * rsqrtf(RV[lane] + EPSV) * G[lane] + BE[lane];
    h[n * 64 + lane] = v > 0.f ? v : expm1f(v);
}

// ---------------- gather (C=7) + log_softmax fused: 8 lanes per node ----------------
__global__ void gather7_final_kernel(const int* __restrict__ rowptr,
                                     const unsigned* __restrict__ es,
                                     const float* __restrict__ Yab7,  // (n,7,2)
                                     const float* __restrict__ Z,
                                     float* __restrict__ out, int n_nodes) {
    int t = blockIdx.x * blockDim.x + threadIdx.x;
    int n = t >> 3;
    int c = t & 7;
    if (n >= n_nodes) return;
    int beg = rowptr[n], end = rowptr[n + 1];
    float acc = 0.f;
    if (c < 7) {
        for (int i = beg; i < end; ++i) {
            unsigned r = es[i];
            float u = __half2float(__ushort_as_half((unsigned short)(r & 0xffffu)));
            float2 ab = *reinterpret_cast<const float2*>(Yab7 + (size_t)(r >> 16) * 14 + 2 * c);
            acc += (1.f - u) * ab.x + u * ab.y;
        }
    }
    float degv = (float)(end - beg);
    if (degv < 1.f) degv = 1.f;
    float v = (c < 7) ? (acc / degv + Z[n * 7 + c]) : -1e30f;
    float m = v;
#pragma unroll
    for (int o = 1; o < 8; o <<= 1) m = fmaxf(m, __shfl_xor(m, o, 8));
    float ex = (c < 7) ? expf(v - m) : 0.f;
    float ssum = ex;
#pragma unroll
    for (int o = 1; o < 8; o <<= 1) ssum += __shfl_xor(ssum, o, 8);
    if (c < 7) out[n * 7 + c] = v - m - logf(ssum);
}

extern "C" void kernel_launch(void* const* d_in, const int* in_sizes, int n_in,
                              void* d_out, int out_size, void* d_ws, size_t ws_size,
                              hipStream_t stream) {
    const float* x    = (const float*)d_in[0];
    const int*   ei   = (const int*)d_in[1];
    const float* attr = (const float*)d_in[2];
    const float* W0 = (const float*)d_in[3];
    const float* R0 = (const float*)d_in[4];
    const float* B0 = (const float*)d_in[5];
    const float* W1 = (const float*)d_in[6];
    const float* R1 = (const float*)d_in[7];
    const float* B1 = (const float*)d_in[8];
    const float* W2 = (const float*)d_in[9];
    const float* R2 = (const float*)d_in[10];
    const float* B2 = (const float*)d_in[11];
    const float* G0  = (const float*)d_in[12];
    const float* BE0 = (const float*)d_in[13];
    const float* RM0 = (const float*)d_in[14];
    const float* RV0 = (const float*)d_in[15];
    const float* G1  = (const float*)d_in[16];
    const float* BE1 = (const float*)d_in[17];
    const float* RM1 = (const float*)d_in[18];
    const float* RV1 = (const float*)d_in[19];

    const int* src = ei;
    const int* dst = ei + NE;
    float* out = (float*)d_out;

    // workspace layout
    char* ws = (char*)d_ws;
    size_t off = 0;
    auto alloc = [&](size_t bytes) { char* p = ws + off; off += (bytes + 255) & ~size_t(255); return p; };
    int*           bcount   = (int*)          alloc(NB * sizeof(int));
    int*           bbase    = (int*)          alloc((NB + 1) * sizeof(int));
    int*           bcursor  = (int*)          alloc(NB * sizeof(int));
    int*           rowptr   = (int*)          alloc((NN + 1) * sizeof(int));
    unsigned*      es1su    = (unsigned*)     alloc((size_t)NE * sizeof(unsigned));
    unsigned char* es1dl    = (unsigned char*)alloc((size_t)NE * sizeof(unsigned char));
    unsigned*      es       = (unsigned*)     alloc((size_t)NE * sizeof(unsigned));
    __half*        Bfrag    = (__half*)       alloc((size_t)2 * 12 * 64 * 8 * sizeof(__half));
    __half2*       YabH     = (__half2*)      alloc((size_t)NN * 64 * sizeof(__half2));
    float*         Yab7     = (float*)        alloc((size_t)NN * 14 * sizeof(float));
    float*         Z        = (float*)        alloc((size_t)NN * 64 * sizeof(float));
    float*         h        = (float*)        alloc((size_t)NN * 64 * sizeof(float));

    const int B = 256;
    const int gN64  = (NN * 64 + B - 1) / B;
    const int gN    = (NN + B - 1) / B;
    const int gN8   = (NN * 8 + B - 1) / B;
    const int gM    = ((NN + 15) / 16 + 3) / 4;   // waves of 16-row M-tiles, 4 per block

    // ---- CSR build via bucketed counting sort (once, reused by all 3 layers) ----
    hipMemsetAsync(bcount, 0, NB * sizeof(int), stream);
    histA_kernel<<<NB, B, 0, stream>>>(dst, bcount, NE);
    bscan_kernel<<<1, 512, 0, stream>>>(bcount, bbase, bcursor);
    binB_kernel<<<NB, B, 0, stream>>>(src, dst, attr, bcursor, es1su, es1dl, NE);
    placeC_kernel<<<NB, B, 0, stream>>>(bbase, es1su, es1dl, rowptr, es);

    // ---- layer 0: F_IN=32 -> H=64 ----
    prepB_kernel<32><<<12, 64, 0, stream>>>(W0, R0, Bfrag);
    gemm_kernel<32><<<gM, B, 0, stream>>>(x, Bfrag, B0, YabH, Z, NN);
    gather64_kernel<<<gN64, B, 0, stream>>>(rowptr, es, YabH, Z, G0, BE0, RM0, RV0, h, NN);

    // ---- layer 1: H=64 -> H=64 ----
    prepB_kernel<64><<<24, 64, 0, stream>>>(W1, R1, Bfrag);
    gemm_kernel<64><<<gM, B, 0, stream>>>(h, Bfrag, B1, YabH, Z, NN);
    gather64_kernel<<<gN64, B, 0, stream>>>(rowptr, es, YabH, Z, G1, BE1, RM1, RV1, h, NN);

    // ---- layer 2: H=64 -> C=7, then log_softmax ----
    matmul7_kernel<<<dim3(gN, 3), B, 0, stream>>>(h, W2, R2, B2, Yab7, Z, NN);
    gather7_final_kernel<<<gN8, B, 0, stream>>>(rowptr, es, Yab7, Z, out, NN);
}

// Round 13
// 260.231 us; speedup vs baseline: 1.4235x; 1.0600x over previous
//
#include <hip/hip_runtime.h>
#include <hip/hip_fp16.h>
#include <math.h>

#define NN 50000
#define NE 800000
#define EPSV 1e-5f
#define BSHIFT 7
#define BSIZE 128
#define NB 391   // ceil(NN / 128)

typedef _Float16 h2f   __attribute__((ext_vector_type(2)));
typedef _Float16 f16x8 __attribute__((ext_vector_type(8)));
typedef float    f32x4 __attribute__((ext_vector_type(4)));

// ---------------- CSR build, phase A: coarse bucket histogram (LDS-aggregated) ----------------
__global__ __launch_bounds__(256) void histA_kernel(const int* __restrict__ dst,
                                                    int* __restrict__ bcount, int E) {
    __shared__ int hist[NB];
    for (int i = threadIdx.x; i < NB; i += blockDim.x) hist[i] = 0;
    __syncthreads();
    int chunk = (E + gridDim.x - 1) / gridDim.x;
    int e0 = blockIdx.x * chunk;
    int e1 = e0 + chunk; if (e1 > E) e1 = E;
    for (int e = e0 + threadIdx.x; e < e1; e += blockDim.x)
        atomicAdd(&hist[dst[e] >> BSHIFT], 1);
    __syncthreads();
    for (int i = threadIdx.x; i < NB; i += blockDim.x)
        if (hist[i]) atomicAdd(&bcount[i], hist[i]);
}

// ---------------- phase B0: exclusive scan of bucket counts -> bbase, bcursor ----------------
__global__ __launch_bounds__(512) void bscan_kernel(const int* __restrict__ bcount,
                                                    int* __restrict__ bbase,
                                                    int* __restrict__ bcursor) {
    __shared__ int wsum[8];
    int t = threadIdx.x;  // 0..511
    int v = (t < NB) ? bcount[t] : 0;
    int incl = v;
#pragma unroll
    for (int o = 1; o < 64; o <<= 1) {
        int nv = __shfl_up(incl, o, 64);
        if ((t & 63) >= o) incl += nv;
    }
    if ((t & 63) == 63) wsum[t >> 6] = incl;
    __syncthreads();
    if (t == 0) {
        int r = 0;
#pragma unroll
        for (int i = 0; i < 8; ++i) { int x = wsum[i]; wsum[i] = r; r += x; }
    }
    __syncthreads();
    int excl = incl - v + wsum[t >> 6];
    if (t <= NB) bbase[t] = excl;     // bbase[NB] == NE
    if (t < NB)  bcursor[t] = excl;
}

// ---------------- phase B: bin edges into bucket-contiguous regions (bulk claims) ----------------
__global__ __launch_bounds__(256) void binB_kernel(const int* __restrict__ src,
                                                   const int* __restrict__ dst,
                                                   const float* __restrict__ attr,
                                                   int* __restrict__ bcursor,
                                                   unsigned* __restrict__ es1su,
                                                   unsigned char* __restrict__ es1dl, int E) {
    __shared__ int hist[NB];
    __shared__ int base[NB];
    for (int i = threadIdx.x; i < NB; i += blockDim.x) hist[i] = 0;
    __syncthreads();
    int chunk = (E + gridDim.x - 1) / gridDim.x;
    int e0 = blockIdx.x * chunk;
    int e1 = e0 + chunk; if (e1 > E) e1 = E;
    for (int e = e0 + threadIdx.x; e < e1; e += blockDim.x)
        atomicAdd(&hist[dst[e] >> BSHIFT], 1);
    __syncthreads();
    for (int i = threadIdx.x; i < NB; i += blockDim.x) {
        int c = hist[i];
        base[i] = c ? atomicAdd(&bcursor[i], c) : 0;
        hist[i] = 0;
    }
    __syncthreads();
    for (int e = e0 + threadIdx.x; e < e1; e += blockDim.x) {
        int d = dst[e];
        int b = d >> BSHIFT;
        int slot = base[b] + atomicAdd(&hist[b], 1);
        __half uh = __float2half_rn(attr[e]);
        es1su[slot] = ((unsigned)src[e] << 16) | (unsigned)__half_as_ushort(uh);
        es1dl[slot] = (unsigned char)(d & (BSIZE - 1));
    }
}

// ---------------- phase C: exact placement within bucket + rowptr (LDS atomics only) ----------------
__global__ __launch_bounds__(256) void placeC_kernel(const int* __restrict__ bbase,
                                                     const unsigned* __restrict__ es1su,
                                                     const unsigned char* __restrict__ es1dl,
                                                     int* __restrict__ rowptr,
                                                     unsigned* __restrict__ es) {
    __shared__ int hist[BSIZE];
    __shared__ int stmp[BSIZE];
    __shared__ int cur[BSIZE];
    int b = blockIdx.x;
    int t = threadIdx.x;
    int bs = bbase[b], be = bbase[b + 1];
    if (t < BSIZE) hist[t] = 0;
    __syncthreads();
    for (int i = bs + t; i < be; i += blockDim.x)
        atomicAdd(&hist[es1dl[i]], 1);
    __syncthreads();
    if (t < BSIZE) {
        int v = hist[t];
        int incl = v;
#pragma unroll
        for (int o = 1; o < 64; o <<= 1) {
            int nv = __shfl_up(incl, o, 64);
            if ((t & 63) >= o) incl += nv;
        }
        stmp[t] = incl;
    }
    __syncthreads();
    if (t < BSIZE) {
        int excl = stmp[t] - hist[t] + ((t >= 64) ? stmp[63] : 0);
        cur[t] = excl;
        int node = b * BSIZE + t;
        if (node < NN) rowptr[node] = bs + excl;
    }
    if (b == NB - 1 && t == 0) rowptr[NN] = NE;
    __syncthreads();
    for (int i = bs + t; i < be; i += blockDim.x) {
        unsigned r = es1su[i];
        int dl = es1dl[i];
        int slot = bs + atomicAdd(&cur[dl], 1);
        es[slot] = r;
    }
}

// ---------------- weight prep (all 3 layers, one launch): pre-swizzled fp16 B-fragments ----------------
// Big layers: Bfrag[((ks*12+nt)*64+lane)*8+j] = B[ks*32+(lane>>4)*8+j][nt*16+(lane&15)]
// Layer 2: 2 N-tiles: nt0 col j<7 = a_j, col 8+j = b_j; nt1 col j<7 = z_j
__global__ __launch_bounds__(64) void prep_all_kernel(
        const float* __restrict__ W0, const float* __restrict__ R0,
        const float* __restrict__ W1, const float* __restrict__ R1,
        const float* __restrict__ W2, const float* __restrict__ R2,
        __half* __restrict__ Bf0, __half* __restrict__ Bf1, __half* __restrict__ Bf7) {
    int lane = threadIdx.x;
    int bid = blockIdx.x;
    int c = lane & 15;
    int kbase = ((lane >> 4) << 3);
    _Float16 vals[8];
    if (bid < 12) {            // layer 0, CIN=32, KS=1
        int nt = bid;
        int n = nt * 16 + c;
#pragma unroll
        for (int j = 0; j < 8; ++j) {
            int k = kbase + j;
            float v;
            if (n < 64)       v = W0[k * 64 + n];
            else if (n < 128) v = W0[32 * 64 + k * 64 + (n - 64)];
            else              v = R0[k * 64 + (n - 128)];
            vals[j] = (_Float16)v;
        }
        *reinterpret_cast<f16x8*>(Bf0 + ((size_t)(bid * 64 + lane)) * 8) =
            *reinterpret_cast<f16x8*>(vals);
    } else if (bid < 36) {     // layer 1, CIN=64, KS=2
        int ksnt = bid - 12;
        int ks = ksnt / 12, nt = ksnt - ks * 12;
        int n = nt * 16 + c;
#pragma unroll
        for (int j = 0; j < 8; ++j) {
            int k = ks * 32 + kbase + j;
            float v;
            if (n < 64)       v = W1[k * 64 + n];
            else if (n < 128) v = W1[64 * 64 + k * 64 + (n - 64)];
            else              v = R1[k * 64 + (n - 128)];
            vals[j] = (_Float16)v;
        }
        *reinterpret_cast<f16x8*>(Bf1 + ((size_t)(ksnt * 64 + lane)) * 8) =
            *reinterpret_cast<f16x8*>(vals);
    } else {                   // layer 2, CIN=64, KS=2, 2 N-tiles
        int ksnt = bid - 36;   // 0..3
        int ks = ksnt >> 1, nt = ksnt & 1;
#pragma unroll
        for (int j = 0; j < 8; ++j) {
            int k = ks * 32 + kbase + j;
            float v = 0.f;
            if (nt == 0) {
                if (c < 7)               v = W2[k * 7 + c];
                else if (c >= 8 && c < 15) v = W2[448 + k * 7 + (c - 8)];
            } else {
                if (c < 7)               v = R2[k * 7 + c];
            }
            vals[j] = (_Float16)v;
        }
        *reinterpret_cast<f16x8*>(Bf7 + ((size_t)(ksnt * 64 + lane)) * 8) =
            *reinterpret_cast<f16x8*>(vals);
    }
}

// ---------------- MFMA GEMM: [YabH | Z] = x @ [Wa|Wb|R] (+bias on Z) ----------------
template<int CIN, bool AHALF>
__global__ __launch_bounds__(256) void gemm_kernel(const void* __restrict__ xin,
                               const __half* __restrict__ Bfrag,
                               const float* __restrict__ Bb,   // (64) bias for Z
                               __half2* __restrict__ YabH,
                               float* __restrict__ Z,
                               int n_nodes) {
    const int lane = threadIdx.x & 63;
    const int wid  = threadIdx.x >> 6;
    int m0 = (blockIdx.x * 4 + wid) * 16;
    if (m0 >= n_nodes) return;
    const int KS = CIN / 32;

    f32x4 acc[12];
#pragma unroll
    for (int i = 0; i < 12; ++i) acc[i] = (f32x4){0.f, 0.f, 0.f, 0.f};

    const int arow = m0 + (lane & 15);
    const int koff = ((lane >> 4) << 3);
    const f16x8* bf = reinterpret_cast<const f16x8*>(Bfrag);
#pragma unroll
    for (int ks = 0; ks < KS; ++ks) {
        f16x8 av;
        if constexpr (AHALF) {
            const _Float16* ap = (const _Float16*)xin + (size_t)arow * CIN + ks * 32 + koff;
            av = *reinterpret_cast<const f16x8*>(ap);
        } else {
            const float* ap = (const float*)xin + (size_t)arow * CIN + ks * 32 + koff;
            float4 a0 = *reinterpret_cast<const float4*>(ap);
            float4 a1 = *reinterpret_cast<const float4*>(ap + 4);
            av[0] = (_Float16)a0.x; av[1] = (_Float16)a0.y;
            av[2] = (_Float16)a0.z; av[3] = (_Float16)a0.w;
            av[4] = (_Float16)a1.x; av[5] = (_Float16)a1.y;
            av[6] = (_Float16)a1.z; av[7] = (_Float16)a1.w;
        }
#pragma unroll
        for (int nt = 0; nt < 12; ++nt) {
            f16x8 bv = bf[(ks * 12 + nt) * 64 + lane];
            acc[nt] = __builtin_amdgcn_mfma_f32_16x16x32_f16(av, bv, acc[nt], 0, 0, 0);
        }
    }

    const int c_lo  = lane & 15;
    const int rbase = ((lane >> 4) << 2);
#pragma unroll
    for (int r = 0; r < 4; ++r) {
        int row = m0 + rbase + r;
#pragma unroll
        for (int nt = 0; nt < 4; ++nt) {
            int c = nt * 16 + c_lo;
            YabH[(size_t)row * 64 + c] = __floats2half2_rn(acc[nt][r], acc[nt + 4][r]);
        }
#pragma unroll
        for (int nt = 8; nt < 12; ++nt) {
            int c = (nt - 8) * 16 + c_lo;
            Z[(size_t)row * 64 + c] = acc[nt][r] + Bb[c];
        }
    }
}

// ---------------- layer-2 MFMA GEMM: [a|b packed, z] from h (fp16), K=64 ----------------
__global__ __launch_bounds__(256) void gemm7_kernel(const __half* __restrict__ h,
                               const __half* __restrict__ Bf7,
                               const float* __restrict__ Bb,    // (7)
                               __half* __restrict__ Yab7H,      // (n,7,2) halves
                               float* __restrict__ Z7,          // (n,7)
                               int n_nodes) {
    const int lane = threadIdx.x & 63;
    const int wid  = threadIdx.x >> 6;
    int m0 = (blockIdx.x * 4 + wid) * 16;
    if (m0 >= n_nodes) return;

    f32x4 acc[2];
    acc[0] = (f32x4){0.f, 0.f, 0.f, 0.f};
    acc[1] = (f32x4){0.f, 0.f, 0.f, 0.f};
    const int arow = m0 + (lane & 15);
    const int koff = ((lane >> 4) << 3);
    const f16x8* bf = reinterpret_cast<const f16x8*>(Bf7);
#pragma unroll
    for (int ks = 0; ks < 2; ++ks) {
        f16x8 av = *reinterpret_cast<const f16x8*>(
            (const _Float16*)h + (size_t)arow * 64 + ks * 32 + koff);
#pragma unroll
        for (int nt = 0; nt < 2; ++nt) {
            f16x8 bv = bf[(ks * 2 + nt) * 64 + lane];
            acc[nt] = __builtin_amdgcn_mfma_f32_16x16x32_f16(av, bv, acc[nt], 0, 0, 0);
        }
    }
    const int c_lo  = lane & 15;
    const int rbase = ((lane >> 4) << 2);
#pragma unroll
    for (int r = 0; r < 4; ++r) {
        int row = m0 + rbase + r;
        if (c_lo < 7) {
            Yab7H[(size_t)row * 14 + 2 * c_lo] = __float2half(acc[0][r]);
            Z7[(size_t)row * 7 + c_lo] = acc[1][r] + Bb[c_lo];
        } else if (c_lo >= 8 && c_lo < 15) {
            Yab7H[(size_t)row * 14 + 2 * (c_lo - 8) + 1] = __float2half(acc[0][r]);
        }
    }
}

// helper: rebuild half2(1-u, u) from the low 16 bits of a record
__device__ inline h2f unpack_u2(unsigned rec) {
    __half uh = __ushort_as_half((unsigned short)(rec & 0xffffu));
    __half one = __ushort_as_half((unsigned short)0x3C00u);
    __half2 p = __halves2half2(__hsub(one, uh), uh);
    return __builtin_bit_cast(h2f, p);
}

// ---------------- gather (H=64) + BN + ELU: one wave per node, int4 es loads, fdot2 ----------------
__global__ void gather64_kernel(const int* __restrict__ rowptr,
                                const unsigned* __restrict__ es,
                                const __half2* __restrict__ YabH,
                                const float* __restrict__ Z,
                                const float* __restrict__ G, const float* __restrict__ BE,
                                const float* __restrict__ RM, const float* __restrict__ RV,
                                __half* __restrict__ h, int n_nodes) {
    int n = (blockIdx.x * blockDim.x + threadIdx.x) >> 6;
    int lane = threadIdx.x & 63;
    if (n >= n_nodes) return;
    int beg = rowptr[n], end = rowptr[n + 1];
    float acc0 = 0.f, acc1 = 0.f, acc2 = 0.f, acc3 = 0.f;
    float acc4 = 0.f, acc5 = 0.f, acc6 = 0.f, acc7 = 0.f;
    int i = beg;
    // peel to 16 B alignment (wave-uniform)
    for (; i < end && (i & 3); ++i) {
        unsigned r0 = es[i];
        __half2 v0 = YabH[(size_t)(r0 >> 16) * 64 + lane];
        acc0 = __builtin_amdgcn_fdot2(__builtin_bit_cast(h2f, v0), unpack_u2(r0), acc0, false);
    }
    for (; i + 7 < end; i += 8) {
        int4 q0 = *reinterpret_cast<const int4*>(es + i);
        int4 q1 = *reinterpret_cast<const int4*>(es + i + 4);
        unsigned r0 = (unsigned)q0.x, r1 = (unsigned)q0.y, r2 = (unsigned)q0.z, r3 = (unsigned)q0.w;
        unsigned r4 = (unsigned)q1.x, r5 = (unsigned)q1.y, r6 = (unsigned)q1.z, r7 = (unsigned)q1.w;
        __half2 v0 = YabH[(size_t)(r0 >> 16) * 64 + lane];
        __half2 v1 = YabH[(size_t)(r1 >> 16) * 64 + lane];
        __half2 v2 = YabH[(size_t)(r2 >> 16) * 64 + lane];
        __half2 v3 = YabH[(size_t)(r3 >> 16) * 64 + lane];
        __half2 v4 = YabH[(size_t)(r4 >> 16) * 64 + lane];
        __half2 v5 = YabH[(size_t)(r5 >> 16) * 64 + lane];
        __half2 v6 = YabH[(size_t)(r6 >> 16) * 64 + lane];
        __half2 v7 = YabH[(size_t)(r7 >> 16) * 64 + lane];
        acc0 = __builtin_amdgcn_fdot2(__builtin_bit_cast(h2f, v0), unpack_u2(r0), acc0, false);
        acc1 = __builtin_amdgcn_fdot2(__builtin_bit_cast(h2f, v1), unpack_u2(r1), acc1, false);
        acc2 = __builtin_amdgcn_fdot2(__builtin_bit_cast(h2f, v2), unpack_u2(r2), acc2, false);
        acc3 = __builtin_amdgcn_fdot2(__builtin_bit_cast(h2f, v3), unpack_u2(r3), acc3, false);
        acc4 = __builtin_amdgcn_fdot2(__builtin_bit_cast(h2f, v4), unpack_u2(r4), acc4, false);
        acc5 = __builtin_amdgcn_fdot2(__builtin_bit_cast(h2f, v5), unpack_u2(r5), acc5, false);
        acc6 = __builtin_amdgcn_fdot2(__builtin_bit_cast(h2f, v6), unpack_u2(r6), acc6, false);
        acc7 = __builtin_amdgcn_fdot2(__builtin_bit_cast(h2f, v7), unpack_u2(r7), acc7, false);
    }
    for (; i + 3 < end; i += 4) {
        int4 q0 = *reinterpret_cast<const int4*>(es + i);
        unsigned r0 = (unsigned)q0.x, r1 = (unsigned)q0.y, r2 = (unsigned)q0.z, r3 = (unsigned)q0.w;
        __half2 v0 = YabH[(size_t)(r0 >> 16) * 64 + lane];
        __half2 v1 = YabH[(size_t)(r1 >> 16) * 64 + lane];
        __half2 v2 = YabH[(size_t)(r2 >> 16) * 64 + lane];
        __half2 v3 = YabH[(size_t)(r3 >> 16) * 64 + lane];
        acc0 = __builtin_amdgcn_fdot2(__builtin_bit_cast(h2f, v0), unpack_u2(r0), acc0, false);
        acc1 = __builtin_amdgcn_fdot2(__builtin_bit_cast(h2f, v1), unpack_u2(r1), acc1, false);
        acc2 = __builtin_amdgcn_fdot2(__builtin_bit_cast(h2f, v2), unpack_u2(r2), acc2, false);
        acc3 = __builtin_amdgcn_fdot2(__builtin_bit_cast(h2f, v3), unpack_u2(r3), acc3, false);
    }
    for (; i < end; ++i) {
        unsigned r0 = es[i];
        __half2 v0 = YabH[(size_t)(r0 >> 16) * 64 + lane];
        acc0 = __builtin_amdgcn_fdot2(__builtin_bit_cast(h2f, v0), unpack_u2(r0), acc0, false);
    }
    float acc = ((acc0 + acc1) + (acc2 + acc3)) + ((acc4 + acc5) + (acc6 + acc7));
    float degv = (float)(end - beg);
    if (degv < 1.f) degv = 1.f;
    float v = acc / degv + Z[n * 64 + lane];
    v = (v - RM[lane]) * rsqrtf(RV[lane] + EPSV) * G[lane] + BE[lane];
    h[(size_t)n * 64 + lane] = __float2half(v > 0.f ? v : expm1f(v));
}

// ---------------- gather (C=7) + log_softmax fused: 8 lanes per node ----------------
__global__ void gather7_final_kernel(const int* __restrict__ rowptr,
                                     const unsigned* __restrict__ es,
                                     const __half2* __restrict__ Yab7H,  // (n,7) half2{a,b}
                                     const float* __restrict__ Z7,
                                     float* __restrict__ out, int n_nodes) {
    int t = blockIdx.x * blockDim.x + threadIdx.x;
    int n = t >> 3;
    int c = t & 7;
    if (n >= n_nodes) return;
    int beg = rowptr[n], end = rowptr[n + 1];
    float acc = 0.f;
    if (c < 7) {
        for (int i = beg; i < end; ++i) {
            unsigned r = es[i];
            __half2 v = Yab7H[(size_t)(r >> 16) * 7 + c];
            acc = __builtin_amdgcn_fdot2(__builtin_bit_cast(h2f, v), unpack_u2(r), acc, false);
        }
    }
    float degv = (float)(end - beg);
    if (degv < 1.f) degv = 1.f;
    float v = (c < 7) ? (acc / degv + Z7[n * 7 + c]) : -1e30f;
    float m = v;
#pragma unroll
    for (int o = 1; o < 8; o <<= 1) m = fmaxf(m, __shfl_xor(m, o, 8));
    float ex = (c < 7) ? expf(v - m) : 0.f;
    float ssum = ex;
#pragma unroll
    for (int o = 1; o < 8; o <<= 1) ssum += __shfl_xor(ssum, o, 8);
    if (c < 7) out[n * 7 + c] = v - m - logf(ssum);
}

extern "C" void kernel_launch(void* const* d_in, const int* in_sizes, int n_in,
                              void* d_out, int out_size, void* d_ws, size_t ws_size,
                              hipStream_t stream) {
    const float* x    = (const float*)d_in[0];
    const int*   ei   = (const int*)d_in[1];
    const float* attr = (const float*)d_in[2];
    const float* W0 = (const float*)d_in[3];
    const float* R0 = (const float*)d_in[4];
    const float* B0 = (const float*)d_in[5];
    const float* W1 = (const float*)d_in[6];
    const float* R1 = (const float*)d_in[7];
    const float* B1 = (const float*)d_in[8];
    const float* W2 = (const float*)d_in[9];
    const float* R2 = (const float*)d_in[10];
    const float* B2 = (const float*)d_in[11];
    const float* G0  = (const float*)d_in[12];
    const float* BE0 = (const float*)d_in[13];
    const float* RM0 = (const float*)d_in[14];
    const float* RV0 = (const float*)d_in[15];
    const float* G1  = (const float*)d_in[16];
    const float* BE1 = (const float*)d_in[17];
    const float* RM1 = (const float*)d_in[18];
    const float* RV1 = (const float*)d_in[19];

    const int* src = ei;
    const int* dst = ei + NE;
    float* out = (float*)d_out;

    // workspace layout
    char* ws = (char*)d_ws;
    size_t off = 0;
    auto alloc = [&](size_t bytes) { char* p = ws + off; off += (bytes + 255) & ~size_t(255); return p; };
    int*           bcount   = (int*)          alloc(NB * sizeof(int));
    int*           bbase    = (int*)          alloc((NB + 1) * sizeof(int));
    int*           bcursor  = (int*)          alloc(NB * sizeof(int));
    int*           rowptr   = (int*)          alloc((NN + 1) * sizeof(int));
    unsigned*      es1su    = (unsigned*)     alloc((size_t)NE * sizeof(unsigned));
    unsigned char* es1dl    = (unsigned char*)alloc((size_t)NE * sizeof(unsigned char));
    unsigned*      es       = (unsigned*)     alloc((size_t)NE * sizeof(unsigned));
    __half*        Bf0      = (__half*)       alloc((size_t)12 * 64 * 8 * sizeof(__half));
    __half*        Bf1      = (__half*)       alloc((size_t)24 * 64 * 8 * sizeof(__half));
    __half*        Bf7      = (__half*)       alloc((size_t)4 * 64 * 8 * sizeof(__half));
    __half2*       YabH     = (__half2*)      alloc((size_t)NN * 64 * sizeof(__half2));
    __half*        Yab7H    = (__half*)       alloc((size_t)NN * 14 * sizeof(__half));
    float*         Z        = (float*)        alloc((size_t)NN * 64 * sizeof(float));
    __half*        h        = (__half*)       alloc((size_t)NN * 64 * sizeof(__half));
    float*         Z7       = (float*)        alloc((size_t)NN * 7 * sizeof(float));

    const int B = 256;
    const int gN64  = (NN * 64 + B - 1) / B;
    const int gN8   = (NN * 8 + B - 1) / B;
    const int gM    = ((NN + 15) / 16 + 3) / 4;   // 16-row M-tiles, 4 waves/block

    // ---- CSR build via bucketed counting sort + weight prep ----
    hipMemsetAsync(bcount, 0, NB * sizeof(int), stream);
    prep_all_kernel<<<40, 64, 0, stream>>>(W0, R0, W1, R1, W2, R2, Bf0, Bf1, Bf7);
    histA_kernel<<<NB, B, 0, stream>>>(dst, bcount, NE);
    bscan_kernel<<<1, 512, 0, stream>>>(bcount, bbase, bcursor);
    binB_kernel<<<NB, B, 0, stream>>>(src, dst, attr, bcursor, es1su, es1dl, NE);
    placeC_kernel<<<NB, B, 0, stream>>>(bbase, es1su, es1dl, rowptr, es);

    // ---- layer 0: F_IN=32 -> H=64 ----
    gemm_kernel<32, false><<<gM, B, 0, stream>>>(x, Bf0, B0, YabH, Z, NN);
    gather64_kernel<<<gN64, B, 0, stream>>>(rowptr, es, YabH, Z, G0, BE0, RM0, RV0, h, NN);

    // ---- layer 1: H=64 -> H=64 ----
    gemm_kernel<64, true><<<gM, B, 0, stream>>>(h, Bf1, B1, YabH, Z, NN);
    gather64_kernel<<<gN64, B, 0, stream>>>(rowptr, es, YabH, Z, G1, BE1, RM1, RV1, h, NN);

    // ---- layer 2: H=64 -> C=7, then log_softmax ----
    gemm7_kernel<<<gM, B, 0, stream>>>(h, Bf7, B2, Yab7H, Z7, NN);
    gather7_final_kernel<<<gN8, B, 0, stream>>>(rowptr, es, (const __half2*)Yab7H, Z7, out, NN);
}

// Round 14
// 241.802 us; speedup vs baseline: 1.5320x; 1.0762x over previous
//
#include <hip/hip_runtime.h>
#include <hip/hip_fp16.h>
#include <math.h>

#define NN 50000
#define NE 800000
#define EPSV 1e-5f
#define BSHIFT 7
#define BSIZE 128
#define NB 391    // ceil(NN / 128)
#define CAP 2560  // slots per bucket; mean load 2046, sigma ~45 -> +11 sigma margin

typedef _Float16 h2f   __attribute__((ext_vector_type(2)));
typedef _Float16 f16x8 __attribute__((ext_vector_type(8)));
typedef float    f32x4 __attribute__((ext_vector_type(4)));

// ---------------- init fixed bucket cursors ----------------
__global__ void initcur_kernel(int* __restrict__ bcursor) {
    int b = blockIdx.x * blockDim.x + threadIdx.x;
    if (b < NB) bcursor[b] = b * CAP;
}

// ---------------- bin edges into fixed-base padded bucket regions (bulk claims) ----------------
__global__ __launch_bounds__(256) void binB_kernel(const int* __restrict__ src,
                                                   const int* __restrict__ dst,
                                                   const float* __restrict__ attr,
                                                   int* __restrict__ bcursor,
                                                   unsigned* __restrict__ es1su,
                                                   unsigned char* __restrict__ es1dl, int E) {
    __shared__ int hist[NB];
    __shared__ int base[NB];
    for (int i = threadIdx.x; i < NB; i += blockDim.x) hist[i] = 0;
    __syncthreads();
    int chunk = (E + gridDim.x - 1) / gridDim.x;
    int e0 = blockIdx.x * chunk;
    int e1 = e0 + chunk; if (e1 > E) e1 = E;
    for (int e = e0 + threadIdx.x; e < e1; e += blockDim.x)
        atomicAdd(&hist[dst[e] >> BSHIFT], 1);
    __syncthreads();
    for (int i = threadIdx.x; i < NB; i += blockDim.x) {
        int c = hist[i];
        base[i] = c ? atomicAdd(&bcursor[i], c) : 0;
        hist[i] = 0;
    }
    __syncthreads();
    for (int e = e0 + threadIdx.x; e < e1; e += blockDim.x) {
        int d = dst[e];
        int b = d >> BSHIFT;
        int slot = base[b] + atomicAdd(&hist[b], 1);
        __half uh = __float2half_rn(attr[e]);
        es1su[slot] = ((unsigned)src[e] << 16) | (unsigned)__half_as_ushort(uh);
        es1dl[slot] = (unsigned char)(d & (BSIZE - 1));
    }
}

// ---------------- exact placement within bucket + per-node {beg,end} (LDS atomics only) ----------------
__global__ __launch_bounds__(256) void placeC_kernel(const int* __restrict__ bcursor,
                                                     const unsigned* __restrict__ es1su,
                                                     const unsigned char* __restrict__ es1dl,
                                                     int2* __restrict__ rowrange,
                                                     unsigned* __restrict__ es) {
    __shared__ int hist[BSIZE];
    __shared__ int stmp[BSIZE];
    __shared__ int cur[BSIZE];
    int b = blockIdx.x;
    int t = threadIdx.x;
    int bs = b * CAP;
    int be = bcursor[b];
    if (t < BSIZE) hist[t] = 0;
    __syncthreads();
    for (int i = bs + t; i < be; i += blockDim.x)
        atomicAdd(&hist[es1dl[i]], 1);
    __syncthreads();
    if (t < BSIZE) {
        int v = hist[t];
        int incl = v;
#pragma unroll
        for (int o = 1; o < 64; o <<= 1) {
            int nv = __shfl_up(incl, o, 64);
            if ((t & 63) >= o) incl += nv;
        }
        stmp[t] = incl;
    }
    __syncthreads();
    if (t < BSIZE) {
        int excl = stmp[t] - hist[t] + ((t >= 64) ? stmp[63] : 0);
        cur[t] = excl;
        int node = b * BSIZE + t;
        if (node < NN) {
            int2 rr; rr.x = bs + excl; rr.y = bs + excl + hist[t];
            rowrange[node] = rr;
        }
    }
    __syncthreads();
    for (int i = bs + t; i < be; i += blockDim.x) {
        unsigned r = es1su[i];
        int dl = es1dl[i];
        int slot = bs + atomicAdd(&cur[dl], 1);
        es[slot] = r;
    }
}

// ---------------- weight prep (all 3 layers, one launch): pre-swizzled fp16 B-fragments ----------------
__global__ __launch_bounds__(64) void prep_all_kernel(
        const float* __restrict__ W0, const float* __restrict__ R0,
        const float* __restrict__ W1, const float* __restrict__ R1,
        const float* __restrict__ W2, const float* __restrict__ R2,
        __half* __restrict__ Bf0, __half* __restrict__ Bf1, __half* __restrict__ Bf7) {
    int lane = threadIdx.x;
    int bid = blockIdx.x;
    int c = lane & 15;
    int kbase = ((lane >> 4) << 3);
    _Float16 vals[8];
    if (bid < 12) {            // layer 0, CIN=32, KS=1
        int nt = bid;
        int n = nt * 16 + c;
#pragma unroll
        for (int j = 0; j < 8; ++j) {
            int k = kbase + j;
            float v;
            if (n < 64)       v = W0[k * 64 + n];
            else if (n < 128) v = W0[32 * 64 + k * 64 + (n - 64)];
            else              v = R0[k * 64 + (n - 128)];
            vals[j] = (_Float16)v;
        }
        *reinterpret_cast<f16x8*>(Bf0 + ((size_t)(bid * 64 + lane)) * 8) =
            *reinterpret_cast<f16x8*>(vals);
    } else if (bid < 36) {     // layer 1, CIN=64, KS=2
        int ksnt = bid - 12;
        int ks = ksnt / 12, nt = ksnt - ks * 12;
        int n = nt * 16 + c;
#pragma unroll
        for (int j = 0; j < 8; ++j) {
            int k = ks * 32 + kbase + j;
            float v;
            if (n < 64)       v = W1[k * 64 + n];
            else if (n < 128) v = W1[64 * 64 + k * 64 + (n - 64)];
            else              v = R1[k * 64 + (n - 128)];
            vals[j] = (_Float16)v;
        }
        *reinterpret_cast<f16x8*>(Bf1 + ((size_t)(ksnt * 64 + lane)) * 8) =
            *reinterpret_cast<f16x8*>(vals);
    } else {                   // layer 2, CIN=64, KS=2, 2 N-tiles
        int ksnt = bid - 36;   // 0..3
        int ks = ksnt >> 1, nt = ksnt & 1;
#pragma unroll
        for (int j = 0; j < 8; ++j) {
            int k = ks * 32 + kbase + j;
            float v = 0.f;
            if (nt == 0) {
                if (c < 7)                 v = W2[k * 7 + c];
                else if (c >= 8 && c < 15) v = W2[448 + k * 7 + (c - 8)];
            } else {
                if (c < 7)                 v = R2[k * 7 + c];
            }
            vals[j] = (_Float16)v;
        }
        *reinterpret_cast<f16x8*>(Bf7 + ((size_t)(ksnt * 64 + lane)) * 8) =
            *reinterpret_cast<f16x8*>(vals);
    }
}

// ---------------- MFMA GEMM: [YabH | Z] = x @ [Wa|Wb|R] (+bias on Z) ----------------
template<int CIN, bool AHALF>
__global__ __launch_bounds__(256) void gemm_kernel(const void* __restrict__ xin,
                               const __half* __restrict__ Bfrag,
                               const float* __restrict__ Bb,   // (64) bias for Z
                               __half2* __restrict__ YabH,
                               float* __restrict__ Z,
                               int n_nodes) {
    const int lane = threadIdx.x & 63;
    const int wid  = threadIdx.x >> 6;
    int m0 = (blockIdx.x * 4 + wid) * 16;
    if (m0 >= n_nodes) return;
    const int KS = CIN / 32;

    f32x4 acc[12];
#pragma unroll
    for (int i = 0; i < 12; ++i) acc[i] = (f32x4){0.f, 0.f, 0.f, 0.f};

    const int arow = m0 + (lane & 15);
    const int koff = ((lane >> 4) << 3);
    const f16x8* bf = reinterpret_cast<const f16x8*>(Bfrag);
#pragma unroll
    for (int ks = 0; ks < KS; ++ks) {
        f16x8 av;
        if constexpr (AHALF) {
            const _Float16* ap = (const _Float16*)xin + (size_t)arow * CIN + ks * 32 + koff;
            av = *reinterpret_cast<const f16x8*>(ap);
        } else {
            const float* ap = (const float*)xin + (size_t)arow * CIN + ks * 32 + koff;
            float4 a0 = *reinterpret_cast<const float4*>(ap);
            float4 a1 = *reinterpret_cast<const float4*>(ap + 4);
            av[0] = (_Float16)a0.x; av[1] = (_Float16)a0.y;
            av[2] = (_Float16)a0.z; av[3] = (_Float16)a0.w;
            av[4] = (_Float16)a1.x; av[5] = (_Float16)a1.y;
            av[6] = (_Float16)a1.z; av[7] = (_Float16)a1.w;
        }
#pragma unroll
        for (int nt = 0; nt < 12; ++nt) {
            f16x8 bv = bf[(ks * 12 + nt) * 64 + lane];
            acc[nt] = __builtin_amdgcn_mfma_f32_16x16x32_f16(av, bv, acc[nt], 0, 0, 0);
        }
    }

    const int c_lo  = lane & 15;
    const int rbase = ((lane >> 4) << 2);
#pragma unroll
    for (int r = 0; r < 4; ++r) {
        int row = m0 + rbase + r;
#pragma unroll
        for (int nt = 0; nt < 4; ++nt) {
            int c = nt * 16 + c_lo;
            YabH[(size_t)row * 64 + c] = __floats2half2_rn(acc[nt][r], acc[nt + 4][r]);
        }
#pragma unroll
        for (int nt = 8; nt < 12; ++nt) {
            int c = (nt - 8) * 16 + c_lo;
            Z[(size_t)row * 64 + c] = acc[nt][r] + Bb[c];
        }
    }
}

// ---------------- layer-2 MFMA GEMM: [a|b packed, z] from h (fp16), K=64 ----------------
__global__ __launch_bounds__(256) void gemm7_kernel(const __half* __restrict__ h,
                               const __half* __restrict__ Bf7,
                               const float* __restrict__ Bb,    // (7)
                               __half* __restrict__ Yab7H,      // (n,7,2) halves
                               float* __restrict__ Z7,          // (n,7)
                               int n_nodes) {
    const int lane = threadIdx.x & 63;
    const int wid  = threadIdx.x >> 6;
    int m0 = (blockIdx.x * 4 + wid) * 16;
    if (m0 >= n_nodes) return;

    f32x4 acc[2];
    acc[0] = (f32x4){0.f, 0.f, 0.f, 0.f};
    acc[1] = (f32x4){0.f, 0.f, 0.f, 0.f};
    const int arow = m0 + (lane & 15);
    const int koff = ((lane >> 4) << 3);
    const f16x8* bf = reinterpret_cast<const f16x8*>(Bf7);
#pragma unroll
    for (int ks = 0; ks < 2; ++ks) {
        f16x8 av = *reinterpret_cast<const f16x8*>(
            (const _Float16*)h + (size_t)arow * 64 + ks * 32 + koff);
#pragma unroll
        for (int nt = 0; nt < 2; ++nt) {
            f16x8 bv = bf[(ks * 2 + nt) * 64 + lane];
            acc[nt] = __builtin_amdgcn_mfma_f32_16x16x32_f16(av, bv, acc[nt], 0, 0, 0);
        }
    }
    const int c_lo  = lane & 15;
    const int rbase = ((lane >> 4) << 2);
#pragma unroll
    for (int r = 0; r < 4; ++r) {
        int row = m0 + rbase + r;
        if (c_lo < 7) {
            Yab7H[(size_t)row * 14 + 2 * c_lo] = __float2half(acc[0][r]);
            Z7[(size_t)row * 7 + c_lo] = acc[1][r] + Bb[c_lo];
        } else if (c_lo >= 8 && c_lo < 15) {
            Yab7H[(size_t)row * 14 + 2 * (c_lo - 8) + 1] = __float2half(acc[0][r]);
        }
    }
}

// helper: rebuild half2(1-u, u) from the low 16 bits of a record
__device__ inline h2f unpack_u2(unsigned rec) {
    __half uh = __ushort_as_half((unsigned short)(rec & 0xffffu));
    __half one = __ushort_as_half((unsigned short)0x3C00u);
    __half2 p = __halves2half2(__hsub(one, uh), uh);
    return __builtin_bit_cast(h2f, p);
}

// ---------------- gather (H=64) + BN + ELU: one wave per node, int4 es loads, fdot2 ----------------
__global__ void gather64_kernel(const int2* __restrict__ rowrange,
                                const unsigned* __restrict__ es,
                                const __half2* __restrict__ YabH,
                                const float* __restrict__ Z,
                                const float* __restrict__ G, const float* __restrict__ BE,
                                const float* __restrict__ RM, const float* __restrict__ RV,
                                __half* __restrict__ h, int n_nodes) {
    int n = (blockIdx.x * blockDim.x + threadIdx.x) >> 6;
    int lane = threadIdx.x & 63;
    if (n >= n_nodes) return;
    int2 rr = rowrange[n];
    int beg = rr.x, end = rr.y;
    float acc0 = 0.f, acc1 = 0.f, acc2 = 0.f, acc3 = 0.f;
    float acc4 = 0.f, acc5 = 0.f, acc6 = 0.f, acc7 = 0.f;
    int i = beg;
    for (; i < end && (i & 3); ++i) {
        unsigned r0 = es[i];
        __half2 v0 = YabH[(size_t)(r0 >> 16) * 64 + lane];
        acc0 = __builtin_amdgcn_fdot2(__builtin_bit_cast(h2f, v0), unpack_u2(r0), acc0, false);
    }
    for (; i + 7 < end; i += 8) {
        int4 q0 = *reinterpret_cast<const int4*>(es + i);
        int4 q1 = *reinterpret_cast<const int4*>(es + i + 4);
        unsigned r0 = (unsigned)q0.x, r1 = (unsigned)q0.y, r2 = (unsigned)q0.z, r3 = (unsigned)q0.w;
        unsigned r4 = (unsigned)q1.x, r5 = (unsigned)q1.y, r6 = (unsigned)q1.z, r7 = (unsigned)q1.w;
        __half2 v0 = YabH[(size_t)(r0 >> 16) * 64 + lane];
        __half2 v1 = YabH[(size_t)(r1 >> 16) * 64 + lane];
        __half2 v2 = YabH[(size_t)(r2 >> 16) * 64 + lane];
        __half2 v3 = YabH[(size_t)(r3 >> 16) * 64 + lane];
        __half2 v4 = YabH[(size_t)(r4 >> 16) * 64 + lane];
        __half2 v5 = YabH[(size_t)(r5 >> 16) * 64 + lane];
        __half2 v6 = YabH[(size_t)(r6 >> 16) * 64 + lane];
        __half2 v7 = YabH[(size_t)(r7 >> 16) * 64 + lane];
        acc0 = __builtin_amdgcn_fdot2(__builtin_bit_cast(h2f, v0), unpack_u2(r0), acc0, false);
        acc1 = __builtin_amdgcn_fdot2(__builtin_bit_cast(h2f, v1), unpack_u2(r1), acc1, false);
        acc2 = __builtin_amdgcn_fdot2(__builtin_bit_cast(h2f, v2), unpack_u2(r2), acc2, false);
        acc3 = __builtin_amdgcn_fdot2(__builtin_bit_cast(h2f, v3), unpack_u2(r3), acc3, false);
        acc4 = __builtin_amdgcn_fdot2(__builtin_bit_cast(h2f, v4), unpack_u2(r4), acc4, false);
        acc5 = __builtin_amdgcn_fdot2(__builtin_bit_cast(h2f, v5), unpack_u2(r5), acc5, false);
        acc6 = __builtin_amdgcn_fdot2(__builtin_bit_cast(h2f, v6), unpack_u2(r6), acc6, false);
        acc7 = __builtin_amdgcn_fdot2(__builtin_bit_cast(h2f, v7), unpack_u2(r7), acc7, false);
    }
    for (; i + 3 < end; i += 4) {
        int4 q0 = *reinterpret_cast<const int4*>(es + i);
        unsigned r0 = (unsigned)q0.x, r1 = (unsigned)q0.y, r2 = (unsigned)q0.z, r3 = (unsigned)q0.w;
        __half2 v0 = YabH[(size_t)(r0 >> 16) * 64 + lane];
        __half2 v1 = YabH[(size_t)(r1 >> 16) * 64 + lane];
        __half2 v2 = YabH[(size_t)(r2 >> 16) * 64 + lane];
        __half2 v3 = YabH[(size_t)(r3 >> 16) * 64 + lane];
        acc0 = __builtin_amdgcn_fdot2(__builtin_bit_cast(h2f, v0), unpack_u2(r0), acc0, false);
        acc1 = __builtin_amdgcn_fdot2(__builtin_bit_cast(h2f, v1), unpack_u2(r1), acc1, false);
        acc2 = __builtin_amdgcn_fdot2(__builtin_bit_cast(h2f, v2), unpack_u2(r2), acc2, false);
        acc3 = __builtin_amdgcn_fdot2(__builtin_bit_cast(h2f, v3), unpack_u2(r3), acc3, false);
    }
    for (; i < end; ++i) {
        unsigned r0 = es[i];
        __half2 v0 = YabH[(size_t)(r0 >> 16) * 64 + lane];
        acc0 = __builtin_amdgcn_fdot2(__builtin_bit_cast(h2f, v0), unpack_u2(r0), acc0, false);
    }
    float acc = ((acc0 + acc1) + (acc2 + acc3)) + ((acc4 + acc5) + (acc6 + acc7));
    float degv = (float)(end - beg);
    if (degv < 1.f) degv = 1.f;
    float v = acc / degv + Z[n * 64 + lane];
    v = (v - RM[lane]) * rsqrtf(RV[lane] + EPSV) * G[lane] + BE[lane];
    h[(size_t)n * 64 + lane] = __float2half(v > 0.f ? v : expm1f(v));
}

// ---------------- gather (C=7) + log_softmax fused: 8 lanes per node ----------------
__global__ void gather7_final_kernel(const int2* __restrict__ rowrange,
                                     const unsigned* __restrict__ es,
                                     const __half2* __restrict__ Yab7H,  // (n,7) half2{a,b}
                                     const float* __restrict__ Z7,
                                     float* __restrict__ out, int n_nodes) {
    int t = blockIdx.x * blockDim.x + threadIdx.x;
    int n = t >> 3;
    int c = t & 7;
    if (n >= n_nodes) return;
    int2 rr = rowrange[n];
    int beg = rr.x, end = rr.y;
    float acc = 0.f;
    if (c < 7) {
        for (int i = beg; i < end; ++i) {
            unsigned r = es[i];
            __half2 v = Yab7H[(size_t)(r >> 16) * 7 + c];
            acc = __builtin_amdgcn_fdot2(__builtin_bit_cast(h2f, v), unpack_u2(r), acc, false);
        }
    }
    float degv = (float)(end - beg);
    if (degv < 1.f) degv = 1.f;
    float v = (c < 7) ? (acc / degv + Z7[n * 7 + c]) : -1e30f;
    float m = v;
#pragma unroll
    for (int o = 1; o < 8; o <<= 1) m = fmaxf(m, __shfl_xor(m, o, 8));
    float ex = (c < 7) ? expf(v - m) : 0.f;
    float ssum = ex;
#pragma unroll
    for (int o = 1; o < 8; o <<= 1) ssum += __shfl_xor(ssum, o, 8);
    if (c < 7) out[n * 7 + c] = v - m - logf(ssum);
}

extern "C" void kernel_launch(void* const* d_in, const int* in_sizes, int n_in,
                              void* d_out, int out_size, void* d_ws, size_t ws_size,
                              hipStream_t stream) {
    const float* x    = (const float*)d_in[0];
    const int*   ei   = (const int*)d_in[1];
    const float* attr = (const float*)d_in[2];
    const float* W0 = (const float*)d_in[3];
    const float* R0 = (const float*)d_in[4];
    const float* B0 = (const float*)d_in[5];
    const float* W1 = (const float*)d_in[6];
    const float* R1 = (const float*)d_in[7];
    const float* B1 = (const float*)d_in[8];
    const float* W2 = (const float*)d_in[9];
    const float* R2 = (const float*)d_in[10];
    const float* B2 = (const float*)d_in[11];
    const float* G0  = (const float*)d_in[12];
    const float* BE0 = (const float*)d_in[13];
    const float* RM0 = (const float*)d_in[14];
    const float* RV0 = (const float*)d_in[15];
    const float* G1  = (const float*)d_in[16];
    const float* BE1 = (const float*)d_in[17];
    const float* RM1 = (const float*)d_in[18];
    const float* RV1 = (const float*)d_in[19];

    const int* src = ei;
    const int* dst = ei + NE;
    float* out = (float*)d_out;

    // workspace layout
    char* ws = (char*)d_ws;
    size_t off = 0;
    auto alloc = [&](size_t bytes) { char* p = ws + off; off += (bytes + 255) & ~size_t(255); return p; };
    int*           bcursor  = (int*)          alloc(NB * sizeof(int));
    int2*          rowrange = (int2*)         alloc((size_t)NN * sizeof(int2));
    unsigned*      es1su    = (unsigned*)     alloc((size_t)NB * CAP * sizeof(unsigned));
    unsigned char* es1dl    = (unsigned char*)alloc((size_t)NB * CAP * sizeof(unsigned char));
    unsigned*      es       = (unsigned*)     alloc((size_t)NB * CAP * sizeof(unsigned));
    __half*        Bf0      = (__half*)       alloc((size_t)12 * 64 * 8 * sizeof(__half));
    __half*        Bf1      = (__half*)       alloc((size_t)24 * 64 * 8 * sizeof(__half));
    __half*        Bf7      = (__half*)       alloc((size_t)4 * 64 * 8 * sizeof(__half));
    __half2*       YabH     = (__half2*)      alloc((size_t)NN * 64 * sizeof(__half2));
    __half*        Yab7H    = (__half*)       alloc((size_t)NN * 14 * sizeof(__half));
    float*         Z        = (float*)        alloc((size_t)NN * 64 * sizeof(float));
    __half*        h        = (__half*)       alloc((size_t)NN * 64 * sizeof(__half));
    float*         Z7       = (float*)        alloc((size_t)NN * 7 * sizeof(float));

    const int B = 256;
    const int gN64  = (NN * 64 + B - 1) / B;
    const int gN8   = (NN * 8 + B - 1) / B;
    const int gM    = ((NN + 15) / 16 + 3) / 4;   // 16-row M-tiles, 4 waves/block

    // ---- CSR build via fixed-base bucketed counting sort + weight prep ----
    initcur_kernel<<<2, 256, 0, stream>>>(bcursor);
    prep_all_kernel<<<40, 64, 0, stream>>>(W0, R0, W1, R1, W2, R2, Bf0, Bf1, Bf7);
    binB_kernel<<<NB, B, 0, stream>>>(src, dst, attr, bcursor, es1su, es1dl, NE);
    placeC_kernel<<<NB, B, 0, stream>>>(bcursor, es1su, es1dl, rowrange, es);

    // ---- layer 0: F_IN=32 -> H=64 ----
    gemm_kernel<32, false><<<gM, B, 0, stream>>>(x, Bf0, B0, YabH, Z, NN);
    gather64_kernel<<<gN64, B, 0, stream>>>(rowrange, es, YabH, Z, G0, BE0, RM0, RV0, h, NN);

    // ---- layer 1: H=64 -> H=64 ----
    gemm_kernel<64, true><<<gM, B, 0, stream>>>(h, Bf1, B1, YabH, Z, NN);
    gather64_kernel<<<gN64, B, 0, stream>>>(rowrange, es, YabH, Z, G1, BE1, RM1, RV1, h, NN);

    // ---- layer 2: H=64 -> C=7, then log_softmax ----
    gemm7_kernel<<<gM, B, 0, stream>>>(h, Bf7, B2, Yab7H, Z7, NN);
    gather7_final_kernel<<<gN8, B, 0, stream>>>(rowrange, es, (const __half2*)Yab7H, Z7, out, NN);
}